// Round 6
// baseline (441.663 us; speedup 1.0000x reference)
//
#include <hip/hip_runtime.h>
#include <math.h>

#define NN 50000
#define RR 8
#define HH 128
#define LL 32
#define EE 1600000

#define FMA4(A, V, C) { A.x += (V).x*(C); A.y += (V).y*(C); A.z += (V).z*(C); A.w += (V).w*(C); }

__device__ __forceinline__ float bflo(unsigned u) { return __uint_as_float(u << 16); }
__device__ __forceinline__ float bfhi(unsigned u) { return __uint_as_float(u & 0xFFFF0000u); }
__device__ __forceinline__ unsigned bfpk(float a, float b) {
    unsigned ua = __float_as_uint(a), ub = __float_as_uint(b);
    ua = (ua + 0x7FFFu + ((ua >> 16) & 1u)) >> 16;
    ub = (ub + 0x7FFFu + ((ub >> 16) & 1u)) >> 16;
    return ua | (ub << 16);
}

// ---- w1 f32 -> bf16 (RNE), 8 elems/thread ----
__global__ __launch_bounds__(256) void conv_w1(const float4* __restrict__ in,
                                               uint4* __restrict__ out) {
    int t = blockIdx.x * blockDim.x + threadIdx.x;   // 6.4M threads
    float4 a = in[2 * (size_t)t], b = in[2 * (size_t)t + 1];
    uint4 o;
    o.x = bfpk(a.x, a.y); o.y = bfpk(a.z, a.w);
    o.z = bfpk(b.x, b.y); o.w = bfpk(b.z, b.w);
    out[t] = o;
}

// ---- count edges per (dst, relation) ----
__global__ void count_kernel(const int* __restrict__ ei, const int* __restrict__ et,
                             unsigned* __restrict__ cnt) {
    int e = blockIdx.x * blockDim.x + threadIdx.x;
    if (e >= EE) return;
    int dst = ei[EE + e];
    int r = et[e];
    atomicAdd(&cnt[dst * RR + r], 1u);
}

// ---- fused: inv = 1/max(cnt,1) in place; per-node totals; block-local scan ----
__global__ void scan_blocks(unsigned* __restrict__ cnt_nr, float* __restrict__ inv,
                            unsigned* __restrict__ node_off, unsigned* __restrict__ bsums) {
    __shared__ unsigned s[256];
    int t = threadIdx.x, g = blockIdx.x * 256 + t;
    unsigned tot = 0;
    if (g < NN) {
        uint4 ca = ((const uint4*)cnt_nr)[g * 2];
        uint4 cb = ((const uint4*)cnt_nr)[g * 2 + 1];
        tot = ca.x + ca.y + ca.z + ca.w + cb.x + cb.y + cb.z + cb.w;
        float4 ia, ib;
        ia.x = ca.x ? 1.f / (float)ca.x : 0.f;
        ia.y = ca.y ? 1.f / (float)ca.y : 0.f;
        ia.z = ca.z ? 1.f / (float)ca.z : 0.f;
        ia.w = ca.w ? 1.f / (float)ca.w : 0.f;
        ib.x = cb.x ? 1.f / (float)cb.x : 0.f;
        ib.y = cb.y ? 1.f / (float)cb.y : 0.f;
        ib.z = cb.z ? 1.f / (float)cb.z : 0.f;
        ib.w = cb.w ? 1.f / (float)cb.w : 0.f;
        ((float4*)inv)[g * 2] = ia;
        ((float4*)inv)[g * 2 + 1] = ib;
    }
    s[t] = tot; __syncthreads();
    for (int off = 1; off < 256; off <<= 1) {
        unsigned u = (t >= off) ? s[t - off] : 0; __syncthreads();
        if (t >= off) s[t] += u; __syncthreads();
    }
    if (g < NN) node_off[g] = s[t] - tot;
    if (t == 255) bsums[blockIdx.x] = s[255];
}

__global__ void scan_top(unsigned* __restrict__ bsums, int nb) {
    __shared__ unsigned s[256];
    int t = threadIdx.x;
    unsigned v = (t < nb) ? bsums[t] : 0;
    s[t] = v; __syncthreads();
    for (int off = 1; off < 256; off <<= 1) {
        unsigned u = (t >= off) ? s[t - off] : 0; __syncthreads();
        if (t >= off) s[t] += u; __syncthreads();
    }
    if (t < nb) bsums[t] = s[t] - v;
}

__global__ void scan_add(unsigned* __restrict__ node_off, const unsigned* __restrict__ bsums,
                         unsigned* __restrict__ cursor, unsigned* __restrict__ srcr) {
    int g = blockIdx.x * 256 + threadIdx.x;
    if (g < NN) {
        unsigned o = node_off[g] + bsums[g >> 8];
        node_off[g] = o;
        cursor[g] = o;
    }
    if (g == 0) node_off[NN] = EE;
    if (g < 16) srcr[EE + g] = 0;  // dummy keys for uniform tails
}

// ---- scatter edges into dst-sorted order, packed key src | (r<<16) ----
__global__ void scatter_kernel(const int* __restrict__ ei, const int* __restrict__ et,
                               unsigned* __restrict__ cursor, unsigned* __restrict__ srcr) {
    int e = blockIdx.x * blockDim.x + threadIdx.x;
    if (e >= EE) return;
    int src = ei[e], dst = ei[EE + e], r = et[e];
    unsigned p = atomicAdd(&cursor[dst], 1u);
    srcr[p] = (unsigned)src | ((unsigned)r << 16);
}

// ---- layer 1 (bf16 w1): wave/node; quarter-wave loads a full 256B row per uint4 instr ----
__global__ __launch_bounds__(256) void l1_gather(const unsigned* __restrict__ node_off,
                                                 const unsigned* __restrict__ srcr,
                                                 const float* __restrict__ inv,
                                                 const uint4* __restrict__ w1b,
                                                 const float* __restrict__ root1,
                                                 const float* __restrict__ bias1,
                                                 float* __restrict__ x) {
    int wid = threadIdx.x >> 6, lane = threadIdx.x & 63;
    int n = blockIdx.x * 4 + wid;
    if (n >= NN) return;
    int q = lane >> 4, ql = lane & 15;
    int beg = node_off[n], end = node_off[n + 1];
    int cnt = end - beg;
    int nfull = cnt >> 4;                    // 16 edges per full iteration
    float myinv = inv[n * RR + (lane & 7)];  // lanes 0..7 hold the 8 inv values
    float4 a0 = {0.f, 0.f, 0.f, 0.f}, a1 = {0.f, 0.f, 0.f, 0.f};
    int e = beg + q;
#define GATH(K, C) {                                                        \
        unsigned ss = (K) & 0xFFFFu, rr = (K) >> 16;                        \
        uint4 v = w1b[((size_t)rr * NN + ss) * 16 + ql];                    \
        a0.x = fmaf(bflo(v.x), (C), a0.x); a0.y = fmaf(bfhi(v.x), (C), a0.y); \
        a0.z = fmaf(bflo(v.y), (C), a0.z); a0.w = fmaf(bfhi(v.y), (C), a0.w); \
        a1.x = fmaf(bflo(v.z), (C), a1.x); a1.y = fmaf(bfhi(v.z), (C), a1.y); \
        a1.z = fmaf(bflo(v.w), (C), a1.z); a1.w = fmaf(bfhi(v.w), (C), a1.w); }
#pragma unroll 1
    for (int it = 0; it < nfull; ++it, e += 16) {
        unsigned k0 = srcr[e], k1 = srcr[e + 4], k2 = srcr[e + 8], k3 = srcr[e + 12];
        float c0 = __shfl(myinv, (int)(k0 >> 16));
        float c1 = __shfl(myinv, (int)(k1 >> 16));
        float c2 = __shfl(myinv, (int)(k2 >> 16));
        float c3 = __shfl(myinv, (int)(k3 >> 16));
        GATH(k0, c0); GATH(k1, c1); GATH(k2, c2); GATH(k3, c3);
    }
    {   // tail: up to 15 edges; shfl wave-uniform, loads guarded (srcr padded +16)
        unsigned k0 = srcr[e], k1 = srcr[e + 4], k2 = srcr[e + 8], k3 = srcr[e + 12];
        float c0 = __shfl(myinv, (int)(k0 >> 16));
        float c1 = __shfl(myinv, (int)(k1 >> 16));
        float c2 = __shfl(myinv, (int)(k2 >> 16));
        float c3 = __shfl(myinv, (int)(k3 >> 16));
        if (e < end)      GATH(k0, c0);
        if (e + 4 < end)  GATH(k1, c1);
        if (e + 8 < end)  GATH(k2, c2);
        if (e + 12 < end) GATH(k3, c3);
    }
#undef GATH
#define RED(c) { c += __shfl_xor(c, 16); c += __shfl_xor(c, 32); }
    RED(a0.x); RED(a0.y); RED(a0.z); RED(a0.w);
    RED(a1.x); RED(a1.y); RED(a1.z); RED(a1.w);
#undef RED
    if (q == 0) {
        const float4* rt = (const float4*)(root1 + (size_t)n * HH);
        const float4* bs = (const float4*)bias1;
        float4 rA = rt[2 * ql], rB = rt[2 * ql + 1];
        float4 bA = bs[2 * ql], bB = bs[2 * ql + 1];
        float4 o0, o1;
        o0.x = fmaxf(a0.x + rA.x + bA.x, 0.f);
        o0.y = fmaxf(a0.y + rA.y + bA.y, 0.f);
        o0.z = fmaxf(a0.z + rA.z + bA.z, 0.f);
        o0.w = fmaxf(a0.w + rA.w + bA.w, 0.f);
        o1.x = fmaxf(a1.x + rB.x + bB.x, 0.f);
        o1.y = fmaxf(a1.y + rB.y + bB.y, 0.f);
        o1.z = fmaxf(a1.z + rB.z + bB.z, 0.f);
        o1.w = fmaxf(a1.w + rB.w + bB.w, 0.f);
        ((float4*)(x + (size_t)n * HH))[2 * ql] = o0;
        ((float4*)(x + (size_t)n * HH))[2 * ql + 1] = o1;
    }
}

// ---- xw: register-blocked GEMM, bf16 output. 32 nodes/block, wave owns 8 nodes ----
__global__ __launch_bounds__(256) void xw_kernel(const float* __restrict__ x,
                                                 const float* __restrict__ w2,
                                                 uint2* __restrict__ xwb) {
    __shared__ float xsT[HH][32];          // 16 KB, x tile transposed
    int t = threadIdx.x;
    int n0 = blockIdx.x * 32;
    {
        int n = t & 31, qq = t >> 5;       // qq: 8 chunks of 16 floats
        int nn = n0 + n; if (nn >= NN) nn = NN - 1;
        const float4* xp = (const float4*)(x + (size_t)nn * HH) + qq * 4;
#pragma unroll
        for (int j = 0; j < 4; ++j) {
            float4 v = xp[j];
            int h = qq * 16 + j * 4;
            xsT[h][n] = v.x; xsT[h + 1][n] = v.y; xsT[h + 2][n] = v.z; xsT[h + 3][n] = v.w;
        }
    }
    __syncthreads();
    int wid = t >> 6, lane = t & 63;
    int nb = wid * 8;
    const float4* wp = (const float4*)w2 + (lane >> 3) * (HH * 8) + (lane & 7);
    float4 acc0 = {0,0,0,0}, acc1 = {0,0,0,0}, acc2 = {0,0,0,0}, acc3 = {0,0,0,0};
    float4 acc4 = {0,0,0,0}, acc5 = {0,0,0,0}, acc6 = {0,0,0,0}, acc7 = {0,0,0,0};
#pragma unroll 8
    for (int h = 0; h < HH; ++h) {
        float4 w = wp[h * 8];
        float4 xa = *(const float4*)(&xsT[h][nb]);
        float4 xb = *(const float4*)(&xsT[h][nb + 4]);
        FMA4(acc0, w, xa.x); FMA4(acc1, w, xa.y); FMA4(acc2, w, xa.z); FMA4(acc3, w, xa.w);
        FMA4(acc4, w, xb.x); FMA4(acc5, w, xb.y); FMA4(acc6, w, xb.z); FMA4(acc7, w, xb.w);
    }
    // row = 256 bf16 = 64 uint2; this lane's slot: (r=lane>>3)*8 + (lane&7)
    uint2* op = xwb + (size_t)(n0 + nb) * 64 + (lane >> 3) * 8 + (lane & 7);
    int rem = NN - (n0 + nb);
#define ST(J, A) if (rem > J) { uint2 u; u.x = bfpk(A.x, A.y); u.y = bfpk(A.z, A.w); op[J * 64] = u; }
    ST(0, acc0) ST(1, acc1) ST(2, acc2) ST(3, acc3)
    ST(4, acc4) ST(5, acc5) ST(6, acc6) ST(7, acc7)
#undef ST
}

// ---- layer 2 (bf16 xw): wave/node; 8 lanes/edge (uint2), 16 edges/iter ----
__global__ __launch_bounds__(256) void l2_gather(const unsigned* __restrict__ node_off,
                                                 const unsigned* __restrict__ srcr,
                                                 const float* __restrict__ inv,
                                                 const uint2* __restrict__ xwb,
                                                 const float* __restrict__ x,
                                                 const float* __restrict__ root2,
                                                 const float* __restrict__ bias2,
                                                 float* __restrict__ out) {
    int wid = threadIdx.x >> 6, lane = threadIdx.x & 63;
    int n = blockIdx.x * 4 + wid;
    if (n >= NN) return;
    int g = lane >> 3, gl = lane & 7;
    int beg = node_off[n], end = node_off[n + 1];
    int cnt = end - beg;
    int nfull = cnt >> 4;                    // 16 edges per full iteration
    float myinv = inv[n * RR + (lane & 7)];
    float4 acc = {0.f, 0.f, 0.f, 0.f};
    int e = beg + g;
#define GATH2(K, C) {                                              \
        unsigned ss = (K) & 0xFFFFu, rr = (K) >> 16;               \
        uint2 v = xwb[((size_t)ss * RR + rr) * 8 + gl];            \
        acc.x = fmaf(bflo(v.x), (C), acc.x);                       \
        acc.y = fmaf(bfhi(v.x), (C), acc.y);                       \
        acc.z = fmaf(bflo(v.y), (C), acc.z);                       \
        acc.w = fmaf(bfhi(v.y), (C), acc.w); }
#pragma unroll 1
    for (int it = 0; it < nfull; ++it, e += 16) {
        unsigned k0 = srcr[e], k1 = srcr[e + 8];
        float c0 = __shfl(myinv, (int)(k0 >> 16));
        float c1 = __shfl(myinv, (int)(k1 >> 16));
        GATH2(k0, c0);
        GATH2(k1, c1);
    }
    {   // tail: up to 15 edges
        unsigned k0 = srcr[e], k1 = srcr[e + 8];
        float c0 = __shfl(myinv, (int)(k0 >> 16));
        float c1 = __shfl(myinv, (int)(k1 >> 16));
        if (e < end)     GATH2(k0, c0);
        if (e + 8 < end) GATH2(k1, c1);
    }
#undef GATH2
    // root2 part: group g covers h in [g*16, g*16+16), gl picks float4 of l
    {
        const float* xp = x + (size_t)n * HH + g * 16;
        const float4* rp = (const float4*)root2 + g * 16 * 8 + gl;
#pragma unroll
        for (int i = 0; i < 16; ++i) {
            float xv = xp[i];
            float4 w = rp[i * 8];
            FMA4(acc, w, xv);
        }
    }
#define RED3(c) { c += __shfl_xor(c, 8); c += __shfl_xor(c, 16); c += __shfl_xor(c, 32); }
    RED3(acc.x); RED3(acc.y); RED3(acc.z); RED3(acc.w);
#undef RED3
    if (lane < 8) {
        float4 b = ((const float4*)bias2)[gl];
        float4 z;
        z.x = 1.f / (1.f + expf(-(acc.x + b.x)));
        z.y = 1.f / (1.f + expf(-(acc.y + b.y)));
        z.z = 1.f / (1.f + expf(-(acc.z + b.z)));
        z.w = 1.f / (1.f + expf(-(acc.w + b.w)));
        ((float4*)(out + (size_t)n * LL))[gl] = z;
    }
}

extern "C" void kernel_launch(void* const* d_in, const int* in_sizes, int n_in,
                              void* d_out, int out_size, void* d_ws, size_t ws_size,
                              hipStream_t stream) {
    const float* w1    = (const float*)d_in[0];
    const float* root1 = (const float*)d_in[1];
    const float* bias1 = (const float*)d_in[2];
    const float* w2    = (const float*)d_in[3];
    const float* root2 = (const float*)d_in[4];
    const float* bias2 = (const float*)d_in[5];
    const int*   ei    = (const int*)d_in[6];
    const int*   et    = (const int*)d_in[7];
    float* out = (float*)d_out;

    // workspace layout (4-byte words; x/w1b/xwb 16B-aligned)
    float*    inv      = (float*)d_ws;                     // @0        400000 (doubles as cnt_nr)
    unsigned* node_off = (unsigned*)(inv + 400000);        // @400000   50001 (pad to 50004)
    unsigned* cursor   = node_off + 50004;                 // @450004   50000
    unsigned* bsums    = cursor + 50000;                   // @500004   256
    unsigned* srcr     = bsums + 256;                      // @500260   1600016
    float*    x        = (float*)(srcr + 1600016);         // @2100276  6400000
    unsigned* w1b      = (unsigned*)(x + 6400000);         // @8500276  25600000 (bf16 w1, 102.4MB)
    unsigned* xwb      = w1b + 25600000;                   // @34100276 6400000  (bf16 xw, 25.6MB)
    // end @40500276 words = 162.0 MB

    hipMemsetAsync(inv, 0, 400000 * sizeof(unsigned), stream);

    const int nb = (NN + 255) / 256;  // 196 scan chunks

    conv_w1<<<25000, 256, 0, stream>>>((const float4*)w1, (uint4*)w1b);
    count_kernel<<<(EE + 255) / 256, 256, 0, stream>>>(ei, et, (unsigned*)inv);
    scan_blocks<<<nb, 256, 0, stream>>>((unsigned*)inv, inv, node_off, bsums);
    scan_top<<<1, 256, 0, stream>>>(bsums, nb);
    scan_add<<<nb, 256, 0, stream>>>(node_off, bsums, cursor, srcr);
    scatter_kernel<<<(EE + 255) / 256, 256, 0, stream>>>(ei, et, cursor, srcr);
    l1_gather<<<(NN + 3) / 4, 256, 0, stream>>>(node_off, srcr, inv, (const uint4*)w1b,
                                                root1, bias1, x);
    xw_kernel<<<(NN + 31) / 32, 256, 0, stream>>>(x, w2, (uint2*)xwb);
    l2_gather<<<(NN + 3) / 4, 256, 0, stream>>>(node_off, srcr, inv, (const uint2*)xwb,
                                                x, root2, bias2, out);
}

// Round 7
// 337.320 us; speedup vs baseline: 1.3093x; 1.3093x over previous
//
#include <hip/hip_runtime.h>
#include <math.h>

#define NN 50000
#define RR 8
#define HH 128
#define LL 32
#define EE 1600000
#define BW 128           // nodes per bucket
#define NB 391           // ceil(NN/BW)

#define FMA4(A, V, C) { A.x += (V).x*(C); A.y += (V).y*(C); A.z += (V).z*(C); A.w += (V).w*(C); }

__device__ __forceinline__ float bflo(unsigned u) { return __uint_as_float(u << 16); }
__device__ __forceinline__ float bfhi(unsigned u) { return __uint_as_float(u & 0xFFFF0000u); }
__device__ __forceinline__ unsigned bfpk(float a, float b) {
    unsigned ua = __float_as_uint(a), ub = __float_as_uint(b);
    ua = (ua + 0x7FFFu + ((ua >> 16) & 1u)) >> 16;
    ub = (ub + 0x7FFFu + ((ub >> 16) & 1u)) >> 16;
    return ua | (ub << 16);
}

// ---- w1 f32 -> bf16 (RNE), 8 elems/thread ----
__global__ __launch_bounds__(256) void conv_w1(const float4* __restrict__ in,
                                               uint4* __restrict__ out) {
    int t = blockIdx.x * blockDim.x + threadIdx.x;   // 6.4M threads
    float4 a = in[2 * (size_t)t], b = in[2 * (size_t)t + 1];
    uint4 o;
    o.x = bfpk(a.x, a.y); o.y = bfpk(a.z, a.w);
    o.z = bfpk(b.x, b.y); o.w = bfpk(b.z, b.w);
    out[t] = o;
}

// ---- A: coarse bucket histogram (LDS-binned) ----
__global__ __launch_bounds__(256) void bhist_kernel(const int* __restrict__ ei,
                                                    unsigned* __restrict__ bcnt) {
    __shared__ unsigned h[NB];
    for (int i = threadIdx.x; i < NB; i += 256) h[i] = 0;
    __syncthreads();
    int base = blockIdx.x * 2048;
#pragma unroll
    for (int k = 0; k < 8; ++k) {
        int e = base + k * 256 + threadIdx.x;
        if (e < EE) atomicAdd(&h[(unsigned)ei[EE + e] >> 7], 1u);
    }
    __syncthreads();
    for (int i = threadIdx.x; i < NB; i += 256)
        if (h[i]) atomicAdd(&bcnt[i], h[i]);
}

// ---- B: scan buckets; init cursors; srcr pad; node_off tail ----
__global__ __launch_bounds__(512) void bscan_kernel(const unsigned* __restrict__ bcnt,
                                                    unsigned* __restrict__ boff,
                                                    unsigned* __restrict__ bcur,
                                                    unsigned* __restrict__ node_off,
                                                    unsigned* __restrict__ srcr) {
    __shared__ unsigned s[512];
    int t = threadIdx.x;
    unsigned v = (t < NB) ? bcnt[t] : 0;
    s[t] = v; __syncthreads();
    for (int off = 1; off < 512; off <<= 1) {
        unsigned u = (t >= off) ? s[t - off] : 0; __syncthreads();
        if (t >= off) s[t] += u; __syncthreads();
    }
    if (t < NB) { unsigned o = s[t] - v; boff[t] = o; bcur[t] = o; }
    if (t == 0) { boff[NB] = EE; node_off[NN] = EE; }
    if (t < 16) srcr[EE + t] = 0;   // dummy keys for uniform gather tails
}

// ---- C: partition edges into coarse buckets, block-contiguous runs ----
__global__ __launch_bounds__(256) void part_kernel(const int* __restrict__ ei,
                                                   const int* __restrict__ et,
                                                   unsigned* __restrict__ bcur,
                                                   unsigned* __restrict__ tmp) {
    __shared__ unsigned h[NB];
    for (int i = threadIdx.x; i < NB; i += 256) h[i] = 0;
    __syncthreads();
    int base = blockIdx.x * 2048;
    unsigned pay[8]; int bk[8];
#pragma unroll
    for (int k = 0; k < 8; ++k) {
        int e = base + k * 256 + threadIdx.x;
        bk[k] = -1;
        if (e < EE) {
            unsigned sN = (unsigned)ei[e], d = (unsigned)ei[EE + e], r = (unsigned)et[e];
            bk[k] = (int)(d >> 7);
            pay[k] = sN | (r << 16) | ((d & 127u) << 19);
            atomicAdd(&h[bk[k]], 1u);
        }
    }
    __syncthreads();
    for (int i = threadIdx.x; i < NB; i += 256) {
        unsigned c = h[i];
        h[i] = c ? atomicAdd(&bcur[i], c) : 0u;   // claim contiguous run
    }
    __syncthreads();
#pragma unroll
    for (int k = 0; k < 8; ++k)
        if (bk[k] >= 0) {
            unsigned p = atomicAdd(&h[bk[k]], 1u);
            tmp[p] = pay[k];
        }
}

// ---- D: per bucket: count per (node,rel) -> inv + node_off, place into srcr ----
__global__ __launch_bounds__(256) void finalize_kernel(const unsigned* __restrict__ boff,
                                                       const unsigned* __restrict__ tmp,
                                                       unsigned* __restrict__ node_off,
                                                       float* __restrict__ inv,
                                                       unsigned* __restrict__ srcr) {
    __shared__ unsigned cnt[BW * RR];   // 4 KB
    __shared__ unsigned cur[BW];
    __shared__ unsigned excl[BW];
    int b = blockIdx.x, t = threadIdx.x;
    unsigned lo = boff[b], hi = boff[b + 1];
    int nn0 = b * BW;
    int nloc = NN - nn0 < BW ? NN - nn0 : BW;
    for (int i = t; i < BW * RR; i += 256) cnt[i] = 0;
    __syncthreads();
    for (unsigned i = lo + t; i < hi; i += 256) {
        unsigned v = tmp[i];
        atomicAdd(&cnt[((v >> 19) & 127u) * RR + ((v >> 16) & 7u)], 1u);
    }
    __syncthreads();
    unsigned own = 0;
    if (t < BW) {
#pragma unroll
        for (int r = 0; r < RR; ++r) own += cnt[t * RR + r];
        excl[t] = own;
    }
    __syncthreads();
    for (int off = 1; off < BW; off <<= 1) {
        unsigned u = 0;
        if (t < BW && t >= off) u = excl[t - off];
        __syncthreads();
        if (t < BW && t >= off) excl[t] += u;
        __syncthreads();
    }
    if (t < nloc) {
        unsigned o = lo + excl[t] - own;   // exclusive
        node_off[nn0 + t] = o;
        cur[t] = o;
    }
    __syncthreads();
    for (int i = t; i < nloc * RR; i += 256) {
        unsigned c = cnt[i];
        inv[(size_t)nn0 * RR + i] = c ? 1.f / (float)c : 0.f;
    }
    for (unsigned i = lo + t; i < hi; i += 256) {
        unsigned v = tmp[i];
        unsigned p = atomicAdd(&cur[(v >> 19) & 127u], 1u);
        srcr[p] = v & 0x7FFFFu;
    }
}

// ---- layer 1 (bf16 w1): wave/node; quarter-wave loads a full 256B row per uint4 instr ----
__global__ __launch_bounds__(256) void l1_gather(const unsigned* __restrict__ node_off,
                                                 const unsigned* __restrict__ srcr,
                                                 const float* __restrict__ inv,
                                                 const uint4* __restrict__ w1b,
                                                 const float* __restrict__ root1,
                                                 const float* __restrict__ bias1,
                                                 float* __restrict__ x) {
    int wid = threadIdx.x >> 6, lane = threadIdx.x & 63;
    int n = blockIdx.x * 4 + wid;
    if (n >= NN) return;
    int q = lane >> 4, ql = lane & 15;
    int beg = node_off[n], end = node_off[n + 1];
    int cnt = end - beg;
    int nfull = cnt >> 4;                    // 16 edges per full iteration
    float myinv = inv[n * RR + (lane & 7)];  // lanes 0..7 hold the 8 inv values
    float4 a0 = {0.f, 0.f, 0.f, 0.f}, a1 = {0.f, 0.f, 0.f, 0.f};
    int e = beg + q;
#define GATH(K, C) {                                                        \
        unsigned ss = (K) & 0xFFFFu, rr = (K) >> 16;                        \
        uint4 v = w1b[((size_t)rr * NN + ss) * 16 + ql];                    \
        a0.x = fmaf(bflo(v.x), (C), a0.x); a0.y = fmaf(bfhi(v.x), (C), a0.y); \
        a0.z = fmaf(bflo(v.y), (C), a0.z); a0.w = fmaf(bfhi(v.y), (C), a0.w); \
        a1.x = fmaf(bflo(v.z), (C), a1.x); a1.y = fmaf(bfhi(v.z), (C), a1.y); \
        a1.z = fmaf(bflo(v.w), (C), a1.z); a1.w = fmaf(bfhi(v.w), (C), a1.w); }
#pragma unroll 1
    for (int it = 0; it < nfull; ++it, e += 16) {
        unsigned k0 = srcr[e], k1 = srcr[e + 4], k2 = srcr[e + 8], k3 = srcr[e + 12];
        float c0 = __shfl(myinv, (int)(k0 >> 16));
        float c1 = __shfl(myinv, (int)(k1 >> 16));
        float c2 = __shfl(myinv, (int)(k2 >> 16));
        float c3 = __shfl(myinv, (int)(k3 >> 16));
        GATH(k0, c0); GATH(k1, c1); GATH(k2, c2); GATH(k3, c3);
    }
    {   // tail: up to 15 edges; shfl wave-uniform, loads guarded (srcr padded +16)
        unsigned k0 = srcr[e], k1 = srcr[e + 4], k2 = srcr[e + 8], k3 = srcr[e + 12];
        float c0 = __shfl(myinv, (int)(k0 >> 16));
        float c1 = __shfl(myinv, (int)(k1 >> 16));
        float c2 = __shfl(myinv, (int)(k2 >> 16));
        float c3 = __shfl(myinv, (int)(k3 >> 16));
        if (e < end)      GATH(k0, c0);
        if (e + 4 < end)  GATH(k1, c1);
        if (e + 8 < end)  GATH(k2, c2);
        if (e + 12 < end) GATH(k3, c3);
    }
#undef GATH
#define RED(c) { c += __shfl_xor(c, 16); c += __shfl_xor(c, 32); }
    RED(a0.x); RED(a0.y); RED(a0.z); RED(a0.w);
    RED(a1.x); RED(a1.y); RED(a1.z); RED(a1.w);
#undef RED
    if (q == 0) {
        const float4* rt = (const float4*)(root1 + (size_t)n * HH);
        const float4* bs = (const float4*)bias1;
        float4 rA = rt[2 * ql], rB = rt[2 * ql + 1];
        float4 bA = bs[2 * ql], bB = bs[2 * ql + 1];
        float4 o0, o1;
        o0.x = fmaxf(a0.x + rA.x + bA.x, 0.f);
        o0.y = fmaxf(a0.y + rA.y + bA.y, 0.f);
        o0.z = fmaxf(a0.z + rA.z + bA.z, 0.f);
        o0.w = fmaxf(a0.w + rA.w + bA.w, 0.f);
        o1.x = fmaxf(a1.x + rB.x + bB.x, 0.f);
        o1.y = fmaxf(a1.y + rB.y + bB.y, 0.f);
        o1.z = fmaxf(a1.z + rB.z + bB.z, 0.f);
        o1.w = fmaxf(a1.w + rB.w + bB.w, 0.f);
        ((float4*)(x + (size_t)n * HH))[2 * ql] = o0;
        ((float4*)(x + (size_t)n * HH))[2 * ql + 1] = o1;
    }
}

// ---- xw: register-blocked GEMM, bf16 output. 32 nodes/block, wave owns 8 nodes ----
__global__ __launch_bounds__(256) void xw_kernel(const float* __restrict__ x,
                                                 const float* __restrict__ w2,
                                                 uint2* __restrict__ xwb) {
    __shared__ float xsT[HH][32];          // 16 KB, x tile transposed
    int t = threadIdx.x;
    int n0 = blockIdx.x * 32;
    {
        int n = t & 31, qq = t >> 5;       // qq: 8 chunks of 16 floats
        int nn = n0 + n; if (nn >= NN) nn = NN - 1;
        const float4* xp = (const float4*)(x + (size_t)nn * HH) + qq * 4;
#pragma unroll
        for (int j = 0; j < 4; ++j) {
            float4 v = xp[j];
            int h = qq * 16 + j * 4;
            xsT[h][n] = v.x; xsT[h + 1][n] = v.y; xsT[h + 2][n] = v.z; xsT[h + 3][n] = v.w;
        }
    }
    __syncthreads();
    int wid = t >> 6, lane = t & 63;
    int nb = wid * 8;
    const float4* wp = (const float4*)w2 + (lane >> 3) * (HH * 8) + (lane & 7);
    float4 acc0 = {0,0,0,0}, acc1 = {0,0,0,0}, acc2 = {0,0,0,0}, acc3 = {0,0,0,0};
    float4 acc4 = {0,0,0,0}, acc5 = {0,0,0,0}, acc6 = {0,0,0,0}, acc7 = {0,0,0,0};
#pragma unroll 8
    for (int h = 0; h < HH; ++h) {
        float4 w = wp[h * 8];
        float4 xa = *(const float4*)(&xsT[h][nb]);
        float4 xb = *(const float4*)(&xsT[h][nb + 4]);
        FMA4(acc0, w, xa.x); FMA4(acc1, w, xa.y); FMA4(acc2, w, xa.z); FMA4(acc3, w, xa.w);
        FMA4(acc4, w, xb.x); FMA4(acc5, w, xb.y); FMA4(acc6, w, xb.z); FMA4(acc7, w, xb.w);
    }
    // row = 256 bf16 = 64 uint2; this lane's slot: (r=lane>>3)*8 + (lane&7)
    uint2* op = xwb + (size_t)(n0 + nb) * 64 + (lane >> 3) * 8 + (lane & 7);
    int rem = NN - (n0 + nb);
#define ST(J, A) if (rem > J) { uint2 u; u.x = bfpk(A.x, A.y); u.y = bfpk(A.z, A.w); op[J * 64] = u; }
    ST(0, acc0) ST(1, acc1) ST(2, acc2) ST(3, acc3)
    ST(4, acc4) ST(5, acc5) ST(6, acc6) ST(7, acc7)
#undef ST
}

// ---- layer 2 (bf16 xw): wave/node; 8 lanes/edge (uint2), 16 edges/iter ----
__global__ __launch_bounds__(256) void l2_gather(const unsigned* __restrict__ node_off,
                                                 const unsigned* __restrict__ srcr,
                                                 const float* __restrict__ inv,
                                                 const uint2* __restrict__ xwb,
                                                 const float* __restrict__ x,
                                                 const float* __restrict__ root2,
                                                 const float* __restrict__ bias2,
                                                 float* __restrict__ out) {
    int wid = threadIdx.x >> 6, lane = threadIdx.x & 63;
    int n = blockIdx.x * 4 + wid;
    if (n >= NN) return;
    int g = lane >> 3, gl = lane & 7;
    int beg = node_off[n], end = node_off[n + 1];
    int cnt = end - beg;
    int nfull = cnt >> 4;                    // 16 edges per full iteration
    float myinv = inv[n * RR + (lane & 7)];
    float4 acc = {0.f, 0.f, 0.f, 0.f};
    int e = beg + g;
#define GATH2(K, C) {                                              \
        unsigned ss = (K) & 0xFFFFu, rr = (K) >> 16;               \
        uint2 v = xwb[((size_t)ss * RR + rr) * 8 + gl];            \
        acc.x = fmaf(bflo(v.x), (C), acc.x);                       \
        acc.y = fmaf(bfhi(v.x), (C), acc.y);                       \
        acc.z = fmaf(bflo(v.y), (C), acc.z);                       \
        acc.w = fmaf(bfhi(v.y), (C), acc.w); }
#pragma unroll 1
    for (int it = 0; it < nfull; ++it, e += 16) {
        unsigned k0 = srcr[e], k1 = srcr[e + 8];
        float c0 = __shfl(myinv, (int)(k0 >> 16));
        float c1 = __shfl(myinv, (int)(k1 >> 16));
        GATH2(k0, c0);
        GATH2(k1, c1);
    }
    {   // tail: up to 15 edges
        unsigned k0 = srcr[e], k1 = srcr[e + 8];
        float c0 = __shfl(myinv, (int)(k0 >> 16));
        float c1 = __shfl(myinv, (int)(k1 >> 16));
        if (e < end)     GATH2(k0, c0);
        if (e + 8 < end) GATH2(k1, c1);
    }
#undef GATH2
    // root2 part: group g covers h in [g*16, g*16+16), gl picks float4 of l
    {
        const float* xp = x + (size_t)n * HH + g * 16;
        const float4* rp = (const float4*)root2 + g * 16 * 8 + gl;
#pragma unroll
        for (int i = 0; i < 16; ++i) {
            float xv = xp[i];
            float4 w = rp[i * 8];
            FMA4(acc, w, xv);
        }
    }
#define RED3(c) { c += __shfl_xor(c, 8); c += __shfl_xor(c, 16); c += __shfl_xor(c, 32); }
    RED3(acc.x); RED3(acc.y); RED3(acc.z); RED3(acc.w);
#undef RED3
    if (lane < 8) {
        float4 b = ((const float4*)bias2)[gl];
        float4 z;
        z.x = 1.f / (1.f + expf(-(acc.x + b.x)));
        z.y = 1.f / (1.f + expf(-(acc.y + b.y)));
        z.z = 1.f / (1.f + expf(-(acc.z + b.z)));
        z.w = 1.f / (1.f + expf(-(acc.w + b.w)));
        ((float4*)(out + (size_t)n * LL))[gl] = z;
    }
}

extern "C" void kernel_launch(void* const* d_in, const int* in_sizes, int n_in,
                              void* d_out, int out_size, void* d_ws, size_t ws_size,
                              hipStream_t stream) {
    const float* w1    = (const float*)d_in[0];
    const float* root1 = (const float*)d_in[1];
    const float* bias1 = (const float*)d_in[2];
    const float* w2    = (const float*)d_in[3];
    const float* root2 = (const float*)d_in[4];
    const float* bias2 = (const float*)d_in[5];
    const int*   ei    = (const int*)d_in[6];
    const int*   et    = (const int*)d_in[7];
    float* out = (float*)d_out;

    // workspace layout (4-byte words; x/w1b/xwb 16B-aligned)
    float*    inv      = (float*)d_ws;                     // @0        400000
    unsigned* node_off = (unsigned*)(inv + 400000);        // @400000   50001 (pad 50004)
    unsigned* bcnt     = node_off + 50004;                 // @450004   391  (pad 400)
    unsigned* boff     = bcnt + 400;                       // @450404   392  (pad 400)
    unsigned* bcur     = boff + 400;                       // @450804   391  (pad 400)
    unsigned* srcr     = bcur + 400;                       // @451204   1600016 (pad 1600020)
    float*    x        = (float*)(srcr + 1600020);         // @2051224  6400000
    unsigned* w1b      = (unsigned*)(x + 6400000);         // @8451224  25600000 (bf16 w1)
    unsigned* xwb      = w1b + 25600000;                   // @34051224 6400000  (bf16 xw)
    unsigned* tmp      = xwb;                              // alias: tmp dead before xwb written
    // end @40451224 words = 161.8 MB

    hipMemsetAsync(bcnt, 0, 400 * sizeof(unsigned), stream);

    conv_w1<<<25000, 256, 0, stream>>>((const float4*)w1, (uint4*)w1b);
    bhist_kernel<<<(EE + 2047) / 2048, 256, 0, stream>>>(ei, bcnt);
    bscan_kernel<<<1, 512, 0, stream>>>(bcnt, boff, bcur, node_off, srcr);
    part_kernel<<<(EE + 2047) / 2048, 256, 0, stream>>>(ei, et, bcur, tmp);
    finalize_kernel<<<NB, 256, 0, stream>>>(boff, tmp, node_off, inv, srcr);
    l1_gather<<<(NN + 3) / 4, 256, 0, stream>>>(node_off, srcr, inv, (const uint4*)w1b,
                                                root1, bias1, x);
    xw_kernel<<<(NN + 31) / 32, 256, 0, stream>>>(x, w2, (uint2*)xwb);
    l2_gather<<<(NN + 3) / 4, 256, 0, stream>>>(node_off, srcr, inv, (const uint2*)xwb,
                                                x, root2, bias2, out);
}

// Round 8
// 332.007 us; speedup vs baseline: 1.3303x; 1.0160x over previous
//
#include <hip/hip_runtime.h>
#include <math.h>

#define NN 50000
#define RR 8
#define HH 128
#define LL 32
#define EE 1600000
#define BW 128           // nodes per bucket
#define NB 391           // ceil(NN/BW)

#define FMA4(A, V, C) { A.x += (V).x*(C); A.y += (V).y*(C); A.z += (V).z*(C); A.w += (V).w*(C); }

__device__ __forceinline__ float bflo(unsigned u) { return __uint_as_float(u << 16); }
__device__ __forceinline__ float bfhi(unsigned u) { return __uint_as_float(u & 0xFFFF0000u); }
__device__ __forceinline__ unsigned bfpk(float a, float b) {
    unsigned ua = __float_as_uint(a), ub = __float_as_uint(b);
    ua = (ua + 0x7FFFu + ((ua >> 16) & 1u)) >> 16;
    ub = (ub + 0x7FFFu + ((ub >> 16) & 1u)) >> 16;
    return ua | (ub << 16);
}

// ---- w1 f32 -> bf16 (RNE), 8 elems/thread; block 0 also zeroes bcnt ----
__global__ __launch_bounds__(256) void conv_w1(const float4* __restrict__ in,
                                               uint4* __restrict__ out,
                                               unsigned* __restrict__ bcnt) {
    int t = blockIdx.x * blockDim.x + threadIdx.x;   // 6.4M threads
    if (blockIdx.x == 0) {
        for (int i = threadIdx.x; i < 400; i += 256) bcnt[i] = 0;
    }
    float4 a = in[2 * (size_t)t], b = in[2 * (size_t)t + 1];
    uint4 o;
    o.x = bfpk(a.x, a.y); o.y = bfpk(a.z, a.w);
    o.z = bfpk(b.x, b.y); o.w = bfpk(b.z, b.w);
    out[t] = o;
}

// ---- A: coarse bucket histogram (LDS-binned) ----
__global__ __launch_bounds__(256) void bhist_kernel(const int* __restrict__ ei,
                                                    unsigned* __restrict__ bcnt) {
    __shared__ unsigned h[NB];
    for (int i = threadIdx.x; i < NB; i += 256) h[i] = 0;
    __syncthreads();
    int base = blockIdx.x * 2048;
#pragma unroll
    for (int k = 0; k < 8; ++k) {
        int e = base + k * 256 + threadIdx.x;
        if (e < EE) atomicAdd(&h[(unsigned)ei[EE + e] >> 7], 1u);
    }
    __syncthreads();
    for (int i = threadIdx.x; i < NB; i += 256)
        if (h[i]) atomicAdd(&bcnt[i], h[i]);
}

// ---- B: scan buckets; init cursors; srcr pad; node_off tail ----
__global__ __launch_bounds__(512) void bscan_kernel(const unsigned* __restrict__ bcnt,
                                                    unsigned* __restrict__ boff,
                                                    unsigned* __restrict__ bcur,
                                                    unsigned* __restrict__ node_off,
                                                    unsigned* __restrict__ srcr) {
    __shared__ unsigned s[512];
    int t = threadIdx.x;
    unsigned v = (t < NB) ? bcnt[t] : 0;
    s[t] = v; __syncthreads();
    for (int off = 1; off < 512; off <<= 1) {
        unsigned u = (t >= off) ? s[t - off] : 0; __syncthreads();
        if (t >= off) s[t] += u; __syncthreads();
    }
    if (t < NB) { unsigned o = s[t] - v; boff[t] = o; bcur[t] = o; }
    if (t == 0) { boff[NB] = EE; node_off[NN] = EE; }
    if (t < 16) srcr[EE + t] = 0;   // dummy keys for uniform gather tails
}

// ---- C: partition edges into coarse buckets, block-contiguous runs ----
__global__ __launch_bounds__(256) void part_kernel(const int* __restrict__ ei,
                                                   const int* __restrict__ et,
                                                   unsigned* __restrict__ bcur,
                                                   unsigned* __restrict__ tmp) {
    __shared__ unsigned h[NB];
    for (int i = threadIdx.x; i < NB; i += 256) h[i] = 0;
    __syncthreads();
    int base = blockIdx.x * 2048;
    unsigned pay[8]; int bk[8];
#pragma unroll
    for (int k = 0; k < 8; ++k) {
        int e = base + k * 256 + threadIdx.x;
        bk[k] = -1;
        if (e < EE) {
            unsigned sN = (unsigned)ei[e], d = (unsigned)ei[EE + e], r = (unsigned)et[e];
            bk[k] = (int)(d >> 7);
            pay[k] = sN | (r << 16) | ((d & 127u) << 19);
            atomicAdd(&h[bk[k]], 1u);
        }
    }
    __syncthreads();
    for (int i = threadIdx.x; i < NB; i += 256) {
        unsigned c = h[i];
        h[i] = c ? atomicAdd(&bcur[i], c) : 0u;   // claim contiguous run
    }
    __syncthreads();
#pragma unroll
    for (int k = 0; k < 8; ++k)
        if (bk[k] >= 0) {
            unsigned p = atomicAdd(&h[bk[k]], 1u);
            tmp[p] = pay[k];
        }
}

// ---- D: per bucket: count per (node,rel) -> inv + node_off, place into srcr ----
__global__ __launch_bounds__(256) void finalize_kernel(const unsigned* __restrict__ boff,
                                                       const unsigned* __restrict__ tmp,
                                                       unsigned* __restrict__ node_off,
                                                       float* __restrict__ inv,
                                                       unsigned* __restrict__ srcr) {
    __shared__ unsigned cnt[BW * RR];   // 4 KB
    __shared__ unsigned cur[BW];
    __shared__ unsigned excl[BW];
    int b = blockIdx.x, t = threadIdx.x;
    unsigned lo = boff[b], hi = boff[b + 1];
    int nn0 = b * BW;
    int nloc = NN - nn0 < BW ? NN - nn0 : BW;
    for (int i = t; i < BW * RR; i += 256) cnt[i] = 0;
    __syncthreads();
    for (unsigned i = lo + t; i < hi; i += 256) {
        unsigned v = tmp[i];
        atomicAdd(&cnt[((v >> 19) & 127u) * RR + ((v >> 16) & 7u)], 1u);
    }
    __syncthreads();
    unsigned own = 0;
    if (t < BW) {
#pragma unroll
        for (int r = 0; r < RR; ++r) own += cnt[t * RR + r];
        excl[t] = own;
    }
    __syncthreads();
    for (int off = 1; off < BW; off <<= 1) {
        unsigned u = 0;
        if (t < BW && t >= off) u = excl[t - off];
        __syncthreads();
        if (t < BW && t >= off) excl[t] += u;
        __syncthreads();
    }
    if (t < nloc) {
        unsigned o = lo + excl[t] - own;   // exclusive
        node_off[nn0 + t] = o;
        cur[t] = o;
    }
    __syncthreads();
    for (int i = t; i < nloc * RR; i += 256) {
        unsigned c = cnt[i];
        inv[(size_t)nn0 * RR + i] = c ? 1.f / (float)c : 0.f;
    }
    for (unsigned i = lo + t; i < hi; i += 256) {
        unsigned v = tmp[i];
        unsigned p = atomicAdd(&cur[(v >> 19) & 127u], 1u);
        srcr[p] = v & 0x7FFFFu;
    }
}

// ---- layer 1 (bf16 w1): wave/node; quarter-wave loads a full 256B row per uint4 instr ----
__global__ __launch_bounds__(256) void l1_gather(const unsigned* __restrict__ node_off,
                                                 const unsigned* __restrict__ srcr,
                                                 const float* __restrict__ inv,
                                                 const uint4* __restrict__ w1b,
                                                 const float* __restrict__ root1,
                                                 const float* __restrict__ bias1,
                                                 float* __restrict__ x) {
    int wid = threadIdx.x >> 6, lane = threadIdx.x & 63;
    int n = blockIdx.x * 4 + wid;
    if (n >= NN) return;
    int q = lane >> 4, ql = lane & 15;
    int beg = node_off[n], end = node_off[n + 1];
    int cnt = end - beg;
    int nfull = cnt >> 4;                    // 16 edges per full iteration
    float myinv = inv[n * RR + (lane & 7)];  // lanes 0..7 hold the 8 inv values
    float4 a0 = {0.f, 0.f, 0.f, 0.f}, a1 = {0.f, 0.f, 0.f, 0.f};
    int e = beg + q;
#define GATH(K, C) {                                                        \
        unsigned ss = (K) & 0xFFFFu, rr = (K) >> 16;                        \
        uint4 v = w1b[((size_t)rr * NN + ss) * 16 + ql];                    \
        a0.x = fmaf(bflo(v.x), (C), a0.x); a0.y = fmaf(bfhi(v.x), (C), a0.y); \
        a0.z = fmaf(bflo(v.y), (C), a0.z); a0.w = fmaf(bfhi(v.y), (C), a0.w); \
        a1.x = fmaf(bflo(v.z), (C), a1.x); a1.y = fmaf(bfhi(v.z), (C), a1.y); \
        a1.z = fmaf(bflo(v.w), (C), a1.z); a1.w = fmaf(bfhi(v.w), (C), a1.w); }
#pragma unroll 1
    for (int it = 0; it < nfull; ++it, e += 16) {
        unsigned k0 = srcr[e], k1 = srcr[e + 4], k2 = srcr[e + 8], k3 = srcr[e + 12];
        float c0 = __shfl(myinv, (int)(k0 >> 16));
        float c1 = __shfl(myinv, (int)(k1 >> 16));
        float c2 = __shfl(myinv, (int)(k2 >> 16));
        float c3 = __shfl(myinv, (int)(k3 >> 16));
        GATH(k0, c0); GATH(k1, c1); GATH(k2, c2); GATH(k3, c3);
    }
    {   // tail: up to 15 edges; shfl wave-uniform, loads guarded (srcr padded +16)
        unsigned k0 = srcr[e], k1 = srcr[e + 4], k2 = srcr[e + 8], k3 = srcr[e + 12];
        float c0 = __shfl(myinv, (int)(k0 >> 16));
        float c1 = __shfl(myinv, (int)(k1 >> 16));
        float c2 = __shfl(myinv, (int)(k2 >> 16));
        float c3 = __shfl(myinv, (int)(k3 >> 16));
        if (e < end)      GATH(k0, c0);
        if (e + 4 < end)  GATH(k1, c1);
        if (e + 8 < end)  GATH(k2, c2);
        if (e + 12 < end) GATH(k3, c3);
    }
#undef GATH
#define RED(c) { c += __shfl_xor(c, 16); c += __shfl_xor(c, 32); }
    RED(a0.x); RED(a0.y); RED(a0.z); RED(a0.w);
    RED(a1.x); RED(a1.y); RED(a1.z); RED(a1.w);
#undef RED
    if (q == 0) {
        const float4* rt = (const float4*)(root1 + (size_t)n * HH);
        const float4* bs = (const float4*)bias1;
        float4 rA = rt[2 * ql], rB = rt[2 * ql + 1];
        float4 bA = bs[2 * ql], bB = bs[2 * ql + 1];
        float4 o0, o1;
        o0.x = fmaxf(a0.x + rA.x + bA.x, 0.f);
        o0.y = fmaxf(a0.y + rA.y + bA.y, 0.f);
        o0.z = fmaxf(a0.z + rA.z + bA.z, 0.f);
        o0.w = fmaxf(a0.w + rA.w + bA.w, 0.f);
        o1.x = fmaxf(a1.x + rB.x + bB.x, 0.f);
        o1.y = fmaxf(a1.y + rB.y + bB.y, 0.f);
        o1.z = fmaxf(a1.z + rB.z + bB.z, 0.f);
        o1.w = fmaxf(a1.w + rB.w + bB.w, 0.f);
        ((float4*)(x + (size_t)n * HH))[2 * ql] = o0;
        ((float4*)(x + (size_t)n * HH))[2 * ql + 1] = o1;
    }
}

// ---- xw: register-blocked GEMM, bf16 output. 32 nodes/block, wave owns 8 nodes ----
__global__ __launch_bounds__(256) void xw_kernel(const float* __restrict__ x,
                                                 const float* __restrict__ w2,
                                                 uint2* __restrict__ xwb) {
    __shared__ float xsT[HH][32];          // 16 KB, x tile transposed
    int t = threadIdx.x;
    int n0 = blockIdx.x * 32;
    {
        int n = t & 31, qq = t >> 5;       // qq: 8 chunks of 16 floats
        int nn = n0 + n; if (nn >= NN) nn = NN - 1;
        const float4* xp = (const float4*)(x + (size_t)nn * HH) + qq * 4;
#pragma unroll
        for (int j = 0; j < 4; ++j) {
            float4 v = xp[j];
            int h = qq * 16 + j * 4;
            xsT[h][n] = v.x; xsT[h + 1][n] = v.y; xsT[h + 2][n] = v.z; xsT[h + 3][n] = v.w;
        }
    }
    __syncthreads();
    int wid = t >> 6, lane = t & 63;
    int nb = wid * 8;
    const float4* wp = (const float4*)w2 + (lane >> 3) * (HH * 8) + (lane & 7);
    float4 acc0 = {0,0,0,0}, acc1 = {0,0,0,0}, acc2 = {0,0,0,0}, acc3 = {0,0,0,0};
    float4 acc4 = {0,0,0,0}, acc5 = {0,0,0,0}, acc6 = {0,0,0,0}, acc7 = {0,0,0,0};
#pragma unroll 8
    for (int h = 0; h < HH; ++h) {
        float4 w = wp[h * 8];
        float4 xa = *(const float4*)(&xsT[h][nb]);
        float4 xb = *(const float4*)(&xsT[h][nb + 4]);
        FMA4(acc0, w, xa.x); FMA4(acc1, w, xa.y); FMA4(acc2, w, xa.z); FMA4(acc3, w, xa.w);
        FMA4(acc4, w, xb.x); FMA4(acc5, w, xb.y); FMA4(acc6, w, xb.z); FMA4(acc7, w, xb.w);
    }
    // row = 256 bf16 = 64 uint2; this lane's slot: (r=lane>>3)*8 + (lane&7)
    uint2* op = xwb + (size_t)(n0 + nb) * 64 + (lane >> 3) * 8 + (lane & 7);
    int rem = NN - (n0 + nb);
#define ST(J, A) if (rem > J) { uint2 u; u.x = bfpk(A.x, A.y); u.y = bfpk(A.z, A.w); op[J * 64] = u; }
    ST(0, acc0) ST(1, acc1) ST(2, acc2) ST(3, acc3)
    ST(4, acc4) ST(5, acc5) ST(6, acc6) ST(7, acc7)
#undef ST
}

// ---- layer 2 (bf16 xw): wave/node; 8 lanes/edge (uint2), 16 edges/iter ----
__global__ __launch_bounds__(256) void l2_gather(const unsigned* __restrict__ node_off,
                                                 const unsigned* __restrict__ srcr,
                                                 const float* __restrict__ inv,
                                                 const uint2* __restrict__ xwb,
                                                 const float* __restrict__ x,
                                                 const float* __restrict__ root2,
                                                 const float* __restrict__ bias2,
                                                 float* __restrict__ out) {
    int wid = threadIdx.x >> 6, lane = threadIdx.x & 63;
    int n = blockIdx.x * 4 + wid;
    if (n >= NN) return;
    int g = lane >> 3, gl = lane & 7;
    int beg = node_off[n], end = node_off[n + 1];
    int cnt = end - beg;
    int nfull = cnt >> 4;                    // 16 edges per full iteration
    float myinv = inv[n * RR + (lane & 7)];
    float4 acc = {0.f, 0.f, 0.f, 0.f};
    int e = beg + g;
#define GATH2(K, C) {                                              \
        unsigned ss = (K) & 0xFFFFu, rr = (K) >> 16;               \
        uint2 v = xwb[((size_t)ss * RR + rr) * 8 + gl];            \
        acc.x = fmaf(bflo(v.x), (C), acc.x);                       \
        acc.y = fmaf(bfhi(v.x), (C), acc.y);                       \
        acc.z = fmaf(bflo(v.y), (C), acc.z);                       \
        acc.w = fmaf(bfhi(v.y), (C), acc.w); }
#pragma unroll 1
    for (int it = 0; it < nfull; ++it, e += 16) {
        unsigned k0 = srcr[e], k1 = srcr[e + 8];
        float c0 = __shfl(myinv, (int)(k0 >> 16));
        float c1 = __shfl(myinv, (int)(k1 >> 16));
        GATH2(k0, c0);
        GATH2(k1, c1);
    }
    {   // tail: up to 15 edges
        unsigned k0 = srcr[e], k1 = srcr[e + 8];
        float c0 = __shfl(myinv, (int)(k0 >> 16));
        float c1 = __shfl(myinv, (int)(k1 >> 16));
        if (e < end)     GATH2(k0, c0);
        if (e + 8 < end) GATH2(k1, c1);
    }
#undef GATH2
    // root2 part: group g covers h in [g*16, g*16+16), gl picks float4 of l
    {
        const float* xp = x + (size_t)n * HH + g * 16;
        const float4* rp = (const float4*)root2 + g * 16 * 8 + gl;
#pragma unroll
        for (int i = 0; i < 16; ++i) {
            float xv = xp[i];
            float4 w = rp[i * 8];
            FMA4(acc, w, xv);
        }
    }
#define RED3(c) { c += __shfl_xor(c, 8); c += __shfl_xor(c, 16); c += __shfl_xor(c, 32); }
    RED3(acc.x); RED3(acc.y); RED3(acc.z); RED3(acc.w);
#undef RED3
    if (lane < 8) {
        float4 b = ((const float4*)bias2)[gl];
        float4 z;
        z.x = 1.f / (1.f + expf(-(acc.x + b.x)));
        z.y = 1.f / (1.f + expf(-(acc.y + b.y)));
        z.z = 1.f / (1.f + expf(-(acc.z + b.z)));
        z.w = 1.f / (1.f + expf(-(acc.w + b.w)));
        ((float4*)(out + (size_t)n * LL))[gl] = z;
    }
}

extern "C" void kernel_launch(void* const* d_in, const int* in_sizes, int n_in,
                              void* d_out, int out_size, void* d_ws, size_t ws_size,
                              hipStream_t stream) {
    const float* w1    = (const float*)d_in[0];
    const float* root1 = (const float*)d_in[1];
    const float* bias1 = (const float*)d_in[2];
    const float* w2    = (const float*)d_in[3];
    const float* root2 = (const float*)d_in[4];
    const float* bias2 = (const float*)d_in[5];
    const int*   ei    = (const int*)d_in[6];
    const int*   et    = (const int*)d_in[7];
    float* out = (float*)d_out;

    // workspace layout (4-byte words; x/w1b/xwb 16B-aligned)
    float*    inv      = (float*)d_ws;                     // @0        400000
    unsigned* node_off = (unsigned*)(inv + 400000);        // @400000   50001 (pad 50004)
    unsigned* bcnt     = node_off + 50004;                 // @450004   391  (pad 400)
    unsigned* boff     = bcnt + 400;                       // @450404   392  (pad 400)
    unsigned* bcur     = boff + 400;                       // @450804   391  (pad 400)
    unsigned* srcr     = bcur + 400;                       // @451204   1600016 (pad 1600020)
    float*    x        = (float*)(srcr + 1600020);         // @2051224  6400000
    unsigned* w1b      = (unsigned*)(x + 6400000);         // @8451224  25600000 (bf16 w1)
    unsigned* xwb      = w1b + 25600000;                   // @34051224 6400000  (bf16 xw)
    unsigned* tmp      = xwb;                              // alias: tmp dead before xwb written
    // end @40451224 words = 161.8 MB

    conv_w1<<<25000, 256, 0, stream>>>((const float4*)w1, (uint4*)w1b, bcnt);
    bhist_kernel<<<(EE + 2047) / 2048, 256, 0, stream>>>(ei, bcnt);
    bscan_kernel<<<1, 512, 0, stream>>>(bcnt, boff, bcur, node_off, srcr);
    part_kernel<<<(EE + 2047) / 2048, 256, 0, stream>>>(ei, et, bcur, tmp);
    finalize_kernel<<<NB, 256, 0, stream>>>(boff, tmp, node_off, inv, srcr);
    l1_gather<<<(NN + 3) / 4, 256, 0, stream>>>(node_off, srcr, inv, (const uint4*)w1b,
                                                root1, bias1, x);
    xw_kernel<<<(NN + 31) / 32, 256, 0, stream>>>(x, w2, (uint2*)xwb);
    l2_gather<<<(NN + 3) / 4, 256, 0, stream>>>(node_off, srcr, inv, (const uint2*)xwb,
                                                x, root2, bias2, out);
}

// Round 9
// 319.078 us; speedup vs baseline: 1.3842x; 1.0405x over previous
//
#include <hip/hip_runtime.h>
#include <math.h>

#define NN 50000
#define RR 8
#define HH 128
#define LL 32
#define EE 1600000
#define BW 128           // nodes per bucket
#define NB 391           // ceil(NN/BW)
#define PB 782           // partition/hist blocks: ceil(E/2048)

#define FMA4(A, V, C) { A.x += (V).x*(C); A.y += (V).y*(C); A.z += (V).z*(C); A.w += (V).w*(C); }

typedef __attribute__((ext_vector_type(8))) short short8_t;
typedef __attribute__((ext_vector_type(4))) float f32x4_t;

__device__ __forceinline__ float bflo(unsigned u) { return __uint_as_float(u << 16); }
__device__ __forceinline__ float bfhi(unsigned u) { return __uint_as_float(u & 0xFFFF0000u); }
__device__ __forceinline__ unsigned bfpk(float a, float b) {
    unsigned ua = __float_as_uint(a), ub = __float_as_uint(b);
    ua = (ua + 0x7FFFu + ((ua >> 16) & 1u)) >> 16;
    ub = (ub + 0x7FFFu + ((ub >> 16) & 1u)) >> 16;
    return ua | (ub << 16);
}
__device__ __forceinline__ unsigned short bf16r(float f) {
    unsigned u = __float_as_uint(f);
    return (unsigned short)((u + 0x7FFFu + ((u >> 16) & 1u)) >> 16);
}

// ---- fused: w1->bf16 (blocks 0..24999); w2->W_T bf16 (block 25000);
//      per-block dst-bucket histograms (blocks 25001..25782) ----
__global__ __launch_bounds__(256) void conv_hist(const float4* __restrict__ w1,
                                                 const float* __restrict__ w2,
                                                 const int* __restrict__ ei,
                                                 uint4* __restrict__ w1b,
                                                 unsigned* __restrict__ wtb,
                                                 unsigned* __restrict__ ph) {
    __shared__ unsigned h[NB];
    int b = blockIdx.x, tid = threadIdx.x;
    if (b < 25000) {
        size_t t = (size_t)b * 256 + tid;
        float4 a = w1[2 * t], c = w1[2 * t + 1];
        uint4 o;
        o.x = bfpk(a.x, a.y); o.y = bfpk(a.z, a.w);
        o.z = bfpk(c.x, c.y); o.w = bfpk(c.z, c.w);
        w1b[t] = o;
    } else if (b == 25000) {
        // W_T[c][k] = w2[c>>5][k][c&31], bf16-packed pairs along k
        int c = tid, r = c >> 5, l = c & 31;
        const float* wp = w2 + (size_t)r * HH * LL + l;
        for (int k = 0; k < HH; k += 2)
            wtb[c * 64 + (k >> 1)] = bfpk(wp[k * LL], wp[(k + 1) * LL]);
    } else {
        int blk = b - 25001;
        for (int i = tid; i < NB; i += 256) h[i] = 0;
        __syncthreads();
        int base = blk * 2048;
#pragma unroll
        for (int k = 0; k < 8; ++k) {
            int e = base + k * 256 + tid;
            if (e < EE) atomicAdd(&h[(unsigned)ei[EE + e] >> 7], 1u);
        }
        __syncthreads();
        for (int i = tid; i < NB; i += 256) ph[blk * NB + i] = h[i];
    }
}

// ---- B: sum partials; scan buckets; init cursors; srcr pad; node_off tail ----
__global__ __launch_bounds__(512) void bscan_kernel(const unsigned* __restrict__ ph,
                                                    unsigned* __restrict__ boff,
                                                    unsigned* __restrict__ bcur,
                                                    unsigned* __restrict__ node_off,
                                                    unsigned* __restrict__ srcr) {
    __shared__ unsigned s[512];
    int t = threadIdx.x;
    unsigned v = 0;
    if (t < NB)
        for (int blk = 0; blk < PB; ++blk) v += ph[blk * NB + t];
    s[t] = v; __syncthreads();
    for (int off = 1; off < 512; off <<= 1) {
        unsigned u = (t >= off) ? s[t - off] : 0; __syncthreads();
        if (t >= off) s[t] += u; __syncthreads();
    }
    if (t < NB) { unsigned o = s[t] - v; boff[t] = o; bcur[t] = o; }
    if (t == 0) { boff[NB] = EE; node_off[NN] = EE; }
    if (t < 16) srcr[EE + t] = 0;   // dummy keys for uniform gather tails
}

// ---- C: partition edges into coarse buckets, block-contiguous runs ----
__global__ __launch_bounds__(256) void part_kernel(const int* __restrict__ ei,
                                                   const int* __restrict__ et,
                                                   unsigned* __restrict__ bcur,
                                                   unsigned* __restrict__ tmp) {
    __shared__ unsigned h[NB];
    for (int i = threadIdx.x; i < NB; i += 256) h[i] = 0;
    __syncthreads();
    int base = blockIdx.x * 2048;
    unsigned pay[8]; int bk[8];
#pragma unroll
    for (int k = 0; k < 8; ++k) {
        int e = base + k * 256 + threadIdx.x;
        bk[k] = -1;
        if (e < EE) {
            unsigned sN = (unsigned)ei[e], d = (unsigned)ei[EE + e], r = (unsigned)et[e];
            bk[k] = (int)(d >> 7);
            pay[k] = sN | (r << 16) | ((d & 127u) << 19);
            atomicAdd(&h[bk[k]], 1u);
        }
    }
    __syncthreads();
    for (int i = threadIdx.x; i < NB; i += 256) {
        unsigned c = h[i];
        h[i] = c ? atomicAdd(&bcur[i], c) : 0u;   // claim contiguous run
    }
    __syncthreads();
#pragma unroll
    for (int k = 0; k < 8; ++k)
        if (bk[k] >= 0) {
            unsigned p = atomicAdd(&h[bk[k]], 1u);
            tmp[p] = pay[k];
        }
}

// ---- D: per bucket: count per (node,rel) -> inv + node_off, place into srcr ----
__global__ __launch_bounds__(256) void finalize_kernel(const unsigned* __restrict__ boff,
                                                       const unsigned* __restrict__ tmp,
                                                       unsigned* __restrict__ node_off,
                                                       float* __restrict__ inv,
                                                       unsigned* __restrict__ srcr) {
    __shared__ unsigned cnt[BW * RR];   // 4 KB
    __shared__ unsigned cur[BW];
    __shared__ unsigned excl[BW];
    int b = blockIdx.x, t = threadIdx.x;
    unsigned lo = boff[b], hi = boff[b + 1];
    int nn0 = b * BW;
    int nloc = NN - nn0 < BW ? NN - nn0 : BW;
    for (int i = t; i < BW * RR; i += 256) cnt[i] = 0;
    __syncthreads();
    for (unsigned i = lo + t; i < hi; i += 256) {
        unsigned v = tmp[i];
        atomicAdd(&cnt[((v >> 19) & 127u) * RR + ((v >> 16) & 7u)], 1u);
    }
    __syncthreads();
    unsigned own = 0;
    if (t < BW) {
#pragma unroll
        for (int r = 0; r < RR; ++r) own += cnt[t * RR + r];
        excl[t] = own;
    }
    __syncthreads();
    for (int off = 1; off < BW; off <<= 1) {
        unsigned u = 0;
        if (t < BW && t >= off) u = excl[t - off];
        __syncthreads();
        if (t < BW && t >= off) excl[t] += u;
        __syncthreads();
    }
    if (t < nloc) {
        unsigned o = lo + excl[t] - own;   // exclusive
        node_off[nn0 + t] = o;
        cur[t] = o;
    }
    __syncthreads();
    for (int i = t; i < nloc * RR; i += 256) {
        unsigned c = cnt[i];
        inv[(size_t)nn0 * RR + i] = c ? 1.f / (float)c : 0.f;
    }
    for (unsigned i = lo + t; i < hi; i += 256) {
        unsigned v = tmp[i];
        unsigned p = atomicAdd(&cur[(v >> 19) & 127u], 1u);
        srcr[p] = v & 0x7FFFFu;
    }
}

// ---- layer 1 (bf16 w1): wave/node; quarter-wave loads a full 256B row per uint4 instr;
//      x written as bf16 ----
__global__ __launch_bounds__(256) void l1_gather(const unsigned* __restrict__ node_off,
                                                 const unsigned* __restrict__ srcr,
                                                 const float* __restrict__ inv,
                                                 const uint4* __restrict__ w1b,
                                                 const float* __restrict__ root1,
                                                 const float* __restrict__ bias1,
                                                 uint4* __restrict__ xb) {
    int wid = threadIdx.x >> 6, lane = threadIdx.x & 63;
    int n = blockIdx.x * 4 + wid;
    if (n >= NN) return;
    int q = lane >> 4, ql = lane & 15;
    int beg = node_off[n], end = node_off[n + 1];
    int cnt = end - beg;
    int nfull = cnt >> 4;                    // 16 edges per full iteration
    float myinv = inv[n * RR + (lane & 7)];  // lanes 0..7 hold the 8 inv values
    float4 a0 = {0.f, 0.f, 0.f, 0.f}, a1 = {0.f, 0.f, 0.f, 0.f};
    int e = beg + q;
#define GATH(K, C) {                                                        \
        unsigned ss = (K) & 0xFFFFu, rr = (K) >> 16;                        \
        uint4 v = w1b[((size_t)rr * NN + ss) * 16 + ql];                    \
        a0.x = fmaf(bflo(v.x), (C), a0.x); a0.y = fmaf(bfhi(v.x), (C), a0.y); \
        a0.z = fmaf(bflo(v.y), (C), a0.z); a0.w = fmaf(bfhi(v.y), (C), a0.w); \
        a1.x = fmaf(bflo(v.z), (C), a1.x); a1.y = fmaf(bfhi(v.z), (C), a1.y); \
        a1.z = fmaf(bflo(v.w), (C), a1.z); a1.w = fmaf(bfhi(v.w), (C), a1.w); }
#pragma unroll 1
    for (int it = 0; it < nfull; ++it, e += 16) {
        unsigned k0 = srcr[e], k1 = srcr[e + 4], k2 = srcr[e + 8], k3 = srcr[e + 12];
        float c0 = __shfl(myinv, (int)(k0 >> 16));
        float c1 = __shfl(myinv, (int)(k1 >> 16));
        float c2 = __shfl(myinv, (int)(k2 >> 16));
        float c3 = __shfl(myinv, (int)(k3 >> 16));
        GATH(k0, c0); GATH(k1, c1); GATH(k2, c2); GATH(k3, c3);
    }
    {   // tail: up to 15 edges; shfl wave-uniform, loads guarded (srcr padded +16)
        unsigned k0 = srcr[e], k1 = srcr[e + 4], k2 = srcr[e + 8], k3 = srcr[e + 12];
        float c0 = __shfl(myinv, (int)(k0 >> 16));
        float c1 = __shfl(myinv, (int)(k1 >> 16));
        float c2 = __shfl(myinv, (int)(k2 >> 16));
        float c3 = __shfl(myinv, (int)(k3 >> 16));
        if (e < end)      GATH(k0, c0);
        if (e + 4 < end)  GATH(k1, c1);
        if (e + 8 < end)  GATH(k2, c2);
        if (e + 12 < end) GATH(k3, c3);
    }
#undef GATH
#define RED(c) { c += __shfl_xor(c, 16); c += __shfl_xor(c, 32); }
    RED(a0.x); RED(a0.y); RED(a0.z); RED(a0.w);
    RED(a1.x); RED(a1.y); RED(a1.z); RED(a1.w);
#undef RED
    if (q == 0) {
        const float4* rt = (const float4*)(root1 + (size_t)n * HH);
        const float4* bs = (const float4*)bias1;
        float4 rA = rt[2 * ql], rB = rt[2 * ql + 1];
        float4 bA = bs[2 * ql], bB = bs[2 * ql + 1];
        float o0 = fmaxf(a0.x + rA.x + bA.x, 0.f);
        float o1 = fmaxf(a0.y + rA.y + bA.y, 0.f);
        float o2 = fmaxf(a0.z + rA.z + bA.z, 0.f);
        float o3 = fmaxf(a0.w + rA.w + bA.w, 0.f);
        float o4 = fmaxf(a1.x + rB.x + bB.x, 0.f);
        float o5 = fmaxf(a1.y + rB.y + bB.y, 0.f);
        float o6 = fmaxf(a1.z + rB.z + bB.z, 0.f);
        float o7 = fmaxf(a1.w + rB.w + bB.w, 0.f);
        uint4 o;
        o.x = bfpk(o0, o1); o.y = bfpk(o2, o3);
        o.z = bfpk(o4, o5); o.w = bfpk(o6, o7);
        xb[(size_t)n * 16 + ql] = o;
    }
}

// ---- xw via MFMA: block = 64 nodes x 64 cols; wave = 16 cols, 4 node-subtiles ----
__global__ __launch_bounds__(256) void xw_mfma(const unsigned* __restrict__ xb,
                                               const unsigned* __restrict__ wtb,
                                               unsigned short* __restrict__ xwb) {
    int tid = threadIdx.x, wid = tid >> 6, l = tid & 63;
    int bn = blockIdx.x >> 2;            // node tile of 64
    int bc = blockIdx.x & 3;             // col quarter
    int col = bc * 64 + wid * 16 + (l & 15);
    int kq = l >> 4;                     // k-chunk within each K-step
    // B fragments for the 4 K-steps (K=128): B[k][n], n=lane&15, k=kq*8+j
    short8_t bfr[4];
    const unsigned* wcol = wtb + col * 64;
#pragma unroll
    for (int ks = 0; ks < 4; ++ks)
        bfr[ks] = *reinterpret_cast<const short8_t*>(wcol + ks * 16 + kq * 4);
    int n0 = bn * 64;
#pragma unroll
    for (int sub = 0; sub < 4; ++sub) {
        int row = n0 + sub * 16 + (l & 15);
        int rc = row < NN ? row : NN - 1;
        const unsigned* xr = xb + (size_t)rc * 64;
        f32x4_t acc = {0.f, 0.f, 0.f, 0.f};
#pragma unroll
        for (int ks = 0; ks < 4; ++ks) {
            short8_t a = *reinterpret_cast<const short8_t*>(xr + ks * 16 + kq * 4);
            acc = __builtin_amdgcn_mfma_f32_16x16x32_bf16(a, bfr[ks], acc, 0, 0, 0);
        }
        int orow0 = n0 + sub * 16 + kq * 4;
#pragma unroll
        for (int j = 0; j < 4; ++j) {
            int orow = orow0 + j;
            if (orow < NN) xwb[(size_t)orow * 256 + col] = bf16r(acc[j]);
        }
    }
}

// ---- layer 2 (bf16 xw): wave/node; 8 lanes/edge (uint2), 16 edges/iter ----
__global__ __launch_bounds__(256) void l2_gather(const unsigned* __restrict__ node_off,
                                                 const unsigned* __restrict__ srcr,
                                                 const float* __restrict__ inv,
                                                 const uint2* __restrict__ xwb,
                                                 const unsigned* __restrict__ xb,
                                                 const float* __restrict__ root2,
                                                 const float* __restrict__ bias2,
                                                 float* __restrict__ out) {
    int wid = threadIdx.x >> 6, lane = threadIdx.x & 63;
    int n = blockIdx.x * 4 + wid;
    if (n >= NN) return;
    int g = lane >> 3, gl = lane & 7;
    int beg = node_off[n], end = node_off[n + 1];
    int cnt = end - beg;
    int nfull = cnt >> 4;                    // 16 edges per full iteration
    float myinv = inv[n * RR + (lane & 7)];
    float4 acc = {0.f, 0.f, 0.f, 0.f};
    int e = beg + g;
#define GATH2(K, C) {                                              \
        unsigned ss = (K) & 0xFFFFu, rr = (K) >> 16;               \
        uint2 v = xwb[((size_t)ss * RR + rr) * 8 + gl];            \
        acc.x = fmaf(bflo(v.x), (C), acc.x);                       \
        acc.y = fmaf(bfhi(v.x), (C), acc.y);                       \
        acc.z = fmaf(bflo(v.y), (C), acc.z);                       \
        acc.w = fmaf(bfhi(v.y), (C), acc.w); }
#pragma unroll 1
    for (int it = 0; it < nfull; ++it, e += 16) {
        unsigned k0 = srcr[e], k1 = srcr[e + 8];
        float c0 = __shfl(myinv, (int)(k0 >> 16));
        float c1 = __shfl(myinv, (int)(k1 >> 16));
        GATH2(k0, c0);
        GATH2(k1, c1);
    }
    {   // tail: up to 15 edges
        unsigned k0 = srcr[e], k1 = srcr[e + 8];
        float c0 = __shfl(myinv, (int)(k0 >> 16));
        float c1 = __shfl(myinv, (int)(k1 >> 16));
        if (e < end)     GATH2(k0, c0);
        if (e + 8 < end) GATH2(k1, c1);
    }
#undef GATH2
    // root2 part: group g covers h in [g*16, g*16+16), gl picks float4 of l
    {
        const uint4* xr = (const uint4*)(xb + (size_t)n * 64);
        uint4 u0 = xr[g * 2], u1 = xr[g * 2 + 1];
        float xv[16] = {bflo(u0.x), bfhi(u0.x), bflo(u0.y), bfhi(u0.y),
                        bflo(u0.z), bfhi(u0.z), bflo(u0.w), bfhi(u0.w),
                        bflo(u1.x), bfhi(u1.x), bflo(u1.y), bfhi(u1.y),
                        bflo(u1.z), bfhi(u1.z), bflo(u1.w), bfhi(u1.w)};
        const float4* rp = (const float4*)root2 + g * 16 * 8 + gl;
#pragma unroll
        for (int i = 0; i < 16; ++i) {
            float4 w = rp[i * 8];
            FMA4(acc, w, xv[i]);
        }
    }
#define RED3(c) { c += __shfl_xor(c, 8); c += __shfl_xor(c, 16); c += __shfl_xor(c, 32); }
    RED3(acc.x); RED3(acc.y); RED3(acc.z); RED3(acc.w);
#undef RED3
    if (lane < 8) {
        float4 b = ((const float4*)bias2)[gl];
        float4 z;
        z.x = 1.f / (1.f + expf(-(acc.x + b.x)));
        z.y = 1.f / (1.f + expf(-(acc.y + b.y)));
        z.z = 1.f / (1.f + expf(-(acc.z + b.z)));
        z.w = 1.f / (1.f + expf(-(acc.w + b.w)));
        ((float4*)(out + (size_t)n * LL))[gl] = z;
    }
}

extern "C" void kernel_launch(void* const* d_in, const int* in_sizes, int n_in,
                              void* d_out, int out_size, void* d_ws, size_t ws_size,
                              hipStream_t stream) {
    const float* w1    = (const float*)d_in[0];
    const float* root1 = (const float*)d_in[1];
    const float* bias1 = (const float*)d_in[2];
    const float* w2    = (const float*)d_in[3];
    const float* root2 = (const float*)d_in[4];
    const float* bias2 = (const float*)d_in[5];
    const int*   ei    = (const int*)d_in[6];
    const int*   et    = (const int*)d_in[7];
    float* out = (float*)d_out;

    // workspace layout (4-byte words; xb/wtb/w1b/xwb 16B-aligned)
    float*    inv      = (float*)d_ws;                     // @0        400000
    unsigned* node_off = (unsigned*)(inv + 400000);        // @400000   50004
    unsigned* boff     = node_off + 50004;                 // @450004   400
    unsigned* bcur     = boff + 400;                       // @450404   400
    unsigned* ph       = bcur + 400;                       // @450804   782*391=305762 (pad 305768)
    unsigned* srcr     = ph + 305768;                      // @756572   1600020
    unsigned* xb       = srcr + 1600020;                   // @2356592  3200000 (bf16 x)
    unsigned* wtb      = xb + 3200000;                     // @5556592  16384   (bf16 W_T)
    unsigned* w1b      = wtb + 16384;                      // @5572976  25600000 (bf16 w1)
    unsigned* xwb      = w1b + 25600000;                   // @31172976 6400000  (bf16 xw)
    unsigned* tmp      = xwb;                              // alias: tmp dead before xwb written
    // end @37572976 words = 150.3 MB

    conv_hist<<<25000 + 1 + PB, 256, 0, stream>>>((const float4*)w1, w2, ei,
                                                  (uint4*)w1b, wtb, ph);
    bscan_kernel<<<1, 512, 0, stream>>>(ph, boff, bcur, node_off, srcr);
    part_kernel<<<PB, 256, 0, stream>>>(ei, et, bcur, tmp);
    finalize_kernel<<<NB, 256, 0, stream>>>(boff, tmp, node_off, inv, srcr);
    l1_gather<<<(NN + 3) / 4, 256, 0, stream>>>(node_off, srcr, inv, (const uint4*)w1b,
                                                root1, bias1, (uint4*)xb);
    xw_mfma<<<((NN + 63) / 64) * 4, 256, 0, stream>>>(xb, wtb, (unsigned short*)xwb);
    l2_gather<<<(NN + 3) / 4, 256, 0, stream>>>(node_off, srcr, inv, (const uint2*)xwb,
                                                xb, root2, bias2, out);
}

// Round 10
// 263.124 us; speedup vs baseline: 1.6785x; 1.2127x over previous
//
#include <hip/hip_runtime.h>
#include <math.h>

#define NN 50000
#define RR 8
#define HH 128
#define LL 32
#define EE 1600000
#define BW 128           // nodes per bucket
#define NB 391           // ceil(NN/BW)
#define PB 782           // partition/hist blocks: ceil(E/2048)

#define FMA4(A, V, C) { A.x += (V).x*(C); A.y += (V).y*(C); A.z += (V).z*(C); A.w += (V).w*(C); }

typedef __attribute__((ext_vector_type(8))) short short8_t;
typedef __attribute__((ext_vector_type(4))) float f32x4_t;

__device__ __forceinline__ float bflo(unsigned u) { return __uint_as_float(u << 16); }
__device__ __forceinline__ float bfhi(unsigned u) { return __uint_as_float(u & 0xFFFF0000u); }
__device__ __forceinline__ unsigned bfpk(float a, float b) {
    unsigned ua = __float_as_uint(a), ub = __float_as_uint(b);
    ua = (ua + 0x7FFFu + ((ua >> 16) & 1u)) >> 16;
    ub = (ub + 0x7FFFu + ((ub >> 16) & 1u)) >> 16;
    return ua | (ub << 16);
}
__device__ __forceinline__ unsigned short bf16r(float f) {
    unsigned u = __float_as_uint(f);
    return (unsigned short)((u + 0x7FFFu + ((u >> 16) & 1u)) >> 16);
}

// ---- 1: per-block dst-bucket histograms (no atomics to global, no zeroing) ----
__global__ __launch_bounds__(256) void hist_kernel(const int* __restrict__ ei,
                                                   unsigned* __restrict__ ph) {
    __shared__ unsigned h[NB];
    int blk = blockIdx.x, tid = threadIdx.x;
    for (int i = tid; i < NB; i += 256) h[i] = 0;
    __syncthreads();
    int base = blk * 2048;
#pragma unroll
    for (int k = 0; k < 8; ++k) {
        int e = base + k * 256 + tid;
        if (e < EE) atomicAdd(&h[(unsigned)ei[EE + e] >> 7], 1u);
    }
    __syncthreads();
    for (int i = tid; i < NB; i += 256) ph[blk * NB + i] = h[i];
}

// ---- 2: parallel reduce of partials: bcnt[b] = sum_blk ph[blk][b] ----
__global__ __launch_bounds__(256) void bred_kernel(const unsigned* __restrict__ ph,
                                                   unsigned* __restrict__ bcnt) {
    __shared__ unsigned s[4];
    int b = blockIdx.x, t = threadIdx.x;
    unsigned v = 0;
    for (int j = t; j < PB; j += 256) v += ph[j * NB + b];
    v += __shfl_down(v, 32); v += __shfl_down(v, 16); v += __shfl_down(v, 8);
    v += __shfl_down(v, 4);  v += __shfl_down(v, 2);  v += __shfl_down(v, 1);
    if ((t & 63) == 0) s[t >> 6] = v;
    __syncthreads();
    if (t == 0) bcnt[b] = s[0] + s[1] + s[2] + s[3];
}

// ---- 3: scan 391 bucket counts; init cursors; srcr pad; node_off tail ----
__global__ __launch_bounds__(512) void bscan_kernel(const unsigned* __restrict__ bcnt,
                                                    unsigned* __restrict__ boff,
                                                    unsigned* __restrict__ bcur,
                                                    unsigned* __restrict__ node_off,
                                                    unsigned* __restrict__ srcr) {
    __shared__ unsigned s[512];
    int t = threadIdx.x;
    unsigned v = (t < NB) ? bcnt[t] : 0;
    s[t] = v; __syncthreads();
    for (int off = 1; off < 512; off <<= 1) {
        unsigned u = (t >= off) ? s[t - off] : 0; __syncthreads();
        if (t >= off) s[t] += u; __syncthreads();
    }
    if (t < NB) { unsigned o = s[t] - v; boff[t] = o; bcur[t] = o; }
    if (t == 0) { boff[NB] = EE; node_off[NN] = EE; }
    if (t < 16) srcr[EE + t] = 0;   // dummy keys for uniform gather tails
}

// ---- 4 (fused): blocks 0..PB-1 partition edges; blocks PB.. convert w1/w2 to bf16.
//      Partition blocks dispatch first; conversion (HBM-bound) backfills -> part is free. ----
__global__ __launch_bounds__(256) void part_conv(const int* __restrict__ ei,
                                                 const int* __restrict__ et,
                                                 unsigned* __restrict__ bcur,
                                                 unsigned* __restrict__ tmp,
                                                 const float4* __restrict__ w1,
                                                 const float* __restrict__ w2,
                                                 uint4* __restrict__ w1b,
                                                 unsigned* __restrict__ wtb) {
    __shared__ unsigned h[NB];
    int b = blockIdx.x, tid = threadIdx.x;
    if (b >= PB) {
        if (b < PB + 25000) {
            size_t t = (size_t)(b - PB) * 256 + tid;
            float4 a = w1[2 * t], c = w1[2 * t + 1];
            uint4 o;
            o.x = bfpk(a.x, a.y); o.y = bfpk(a.z, a.w);
            o.z = bfpk(c.x, c.y); o.w = bfpk(c.z, c.w);
            w1b[t] = o;
        } else {
            // W_T[c][k] = w2[c>>5][k][c&31], bf16-packed pairs along k
            int c = tid, r = c >> 5, l = c & 31;
            const float* wp = w2 + (size_t)r * HH * LL + l;
            for (int k = 0; k < HH; k += 2)
                wtb[c * 64 + (k >> 1)] = bfpk(wp[k * LL], wp[(k + 1) * LL]);
        }
        return;
    }
    for (int i = tid; i < NB; i += 256) h[i] = 0;
    __syncthreads();
    int base = b * 2048;
    unsigned pay[8]; int bk[8];
#pragma unroll
    for (int k = 0; k < 8; ++k) {
        int e = base + k * 256 + tid;
        bk[k] = -1;
        if (e < EE) {
            unsigned sN = (unsigned)ei[e], d = (unsigned)ei[EE + e], r = (unsigned)et[e];
            bk[k] = (int)(d >> 7);
            pay[k] = sN | (r << 16) | ((d & 127u) << 19);
            atomicAdd(&h[bk[k]], 1u);
        }
    }
    __syncthreads();
    for (int i = tid; i < NB; i += 256) {
        unsigned c = h[i];
        h[i] = c ? atomicAdd(&bcur[i], c) : 0u;   // claim contiguous run
    }
    __syncthreads();
#pragma unroll
    for (int k = 0; k < 8; ++k)
        if (bk[k] >= 0) {
            unsigned p = atomicAdd(&h[bk[k]], 1u);
            tmp[p] = pay[k];
        }
}

// ---- 5: per bucket: count per (node,rel) -> inv + node_off, place into srcr ----
__global__ __launch_bounds__(256) void finalize_kernel(const unsigned* __restrict__ boff,
                                                       const unsigned* __restrict__ tmp,
                                                       unsigned* __restrict__ node_off,
                                                       float* __restrict__ inv,
                                                       unsigned* __restrict__ srcr) {
    __shared__ unsigned cnt[BW * RR];   // 4 KB
    __shared__ unsigned cur[BW];
    __shared__ unsigned excl[BW];
    int b = blockIdx.x, t = threadIdx.x;
    unsigned lo = boff[b], hi = boff[b + 1];
    int nn0 = b * BW;
    int nloc = NN - nn0 < BW ? NN - nn0 : BW;
    for (int i = t; i < BW * RR; i += 256) cnt[i] = 0;
    __syncthreads();
    for (unsigned i = lo + t; i < hi; i += 256) {
        unsigned v = tmp[i];
        atomicAdd(&cnt[((v >> 19) & 127u) * RR + ((v >> 16) & 7u)], 1u);
    }
    __syncthreads();
    unsigned own = 0;
    if (t < BW) {
#pragma unroll
        for (int r = 0; r < RR; ++r) own += cnt[t * RR + r];
        excl[t] = own;
    }
    __syncthreads();
    for (int off = 1; off < BW; off <<= 1) {
        unsigned u = 0;
        if (t < BW && t >= off) u = excl[t - off];
        __syncthreads();
        if (t < BW && t >= off) excl[t] += u;
        __syncthreads();
    }
    if (t < nloc) {
        unsigned o = lo + excl[t] - own;   // exclusive
        node_off[nn0 + t] = o;
        cur[t] = o;
    }
    __syncthreads();
    for (int i = t; i < nloc * RR; i += 256) {
        unsigned c = cnt[i];
        inv[(size_t)nn0 * RR + i] = c ? 1.f / (float)c : 0.f;
    }
    for (unsigned i = lo + t; i < hi; i += 256) {
        unsigned v = tmp[i];
        unsigned p = atomicAdd(&cur[(v >> 19) & 127u], 1u);
        srcr[p] = v & 0x7FFFFu;
    }
}

// ---- 6: layer 1 (bf16 w1): wave/node; quarter-wave per edge; key prefetch pipeline ----
__global__ __launch_bounds__(256) void l1_gather(const unsigned* __restrict__ node_off,
                                                 const unsigned* __restrict__ srcr,
                                                 const float* __restrict__ inv,
                                                 const uint4* __restrict__ w1b,
                                                 const float* __restrict__ root1,
                                                 const float* __restrict__ bias1,
                                                 uint4* __restrict__ xb) {
    int wid = threadIdx.x >> 6, lane = threadIdx.x & 63;
    int n = blockIdx.x * 4 + wid;
    if (n >= NN) return;
    int q = lane >> 4, ql = lane & 15;
    int beg = node_off[n], end = node_off[n + 1];
    int cnt = end - beg;
    int nfull = cnt >> 4;                    // 16 edges per full iteration
    float myinv = inv[n * RR + (lane & 7)];  // lanes 0..7 hold the 8 inv values
    float4 a0 = {0.f, 0.f, 0.f, 0.f}, a1 = {0.f, 0.f, 0.f, 0.f};
    int e = beg + q;
    // prefetched keys (srcr padded +16 past EE, so always safe)
    unsigned kp0 = srcr[e], kp1 = srcr[e + 4], kp2 = srcr[e + 8], kp3 = srcr[e + 12];
#define GATH(K, C) {                                                        \
        unsigned ss = (K) & 0xFFFFu, rr = (K) >> 16;                        \
        uint4 v = w1b[((size_t)rr * NN + ss) * 16 + ql];                    \
        a0.x = fmaf(bflo(v.x), (C), a0.x); a0.y = fmaf(bfhi(v.x), (C), a0.y); \
        a0.z = fmaf(bflo(v.y), (C), a0.z); a0.w = fmaf(bfhi(v.y), (C), a0.w); \
        a1.x = fmaf(bflo(v.z), (C), a1.x); a1.y = fmaf(bfhi(v.z), (C), a1.y); \
        a1.z = fmaf(bflo(v.w), (C), a1.z); a1.w = fmaf(bfhi(v.w), (C), a1.w); }
#pragma unroll 1
    for (int it = 0; it < nfull; ++it) {
        unsigned k0 = kp0, k1 = kp1, k2 = kp2, k3 = kp3;
        e += 16;
        kp0 = srcr[e]; kp1 = srcr[e + 4]; kp2 = srcr[e + 8]; kp3 = srcr[e + 12];
        float c0 = __shfl(myinv, (int)(k0 >> 16));
        float c1 = __shfl(myinv, (int)(k1 >> 16));
        float c2 = __shfl(myinv, (int)(k2 >> 16));
        float c3 = __shfl(myinv, (int)(k3 >> 16));
        GATH(k0, c0); GATH(k1, c1); GATH(k2, c2); GATH(k3, c3);
    }
    {   // tail: up to 15 edges; keys already prefetched; loads guarded
        float c0 = __shfl(myinv, (int)(kp0 >> 16));
        float c1 = __shfl(myinv, (int)(kp1 >> 16));
        float c2 = __shfl(myinv, (int)(kp2 >> 16));
        float c3 = __shfl(myinv, (int)(kp3 >> 16));
        if (e < end)      GATH(kp0, c0);
        if (e + 4 < end)  GATH(kp1, c1);
        if (e + 8 < end)  GATH(kp2, c2);
        if (e + 12 < end) GATH(kp3, c3);
    }
#undef GATH
#define RED(c) { c += __shfl_xor(c, 16); c += __shfl_xor(c, 32); }
    RED(a0.x); RED(a0.y); RED(a0.z); RED(a0.w);
    RED(a1.x); RED(a1.y); RED(a1.z); RED(a1.w);
#undef RED
    if (q == 0) {
        const float4* rt = (const float4*)(root1 + (size_t)n * HH);
        const float4* bs = (const float4*)bias1;
        float4 rA = rt[2 * ql], rB = rt[2 * ql + 1];
        float4 bA = bs[2 * ql], bB = bs[2 * ql + 1];
        float o0 = fmaxf(a0.x + rA.x + bA.x, 0.f);
        float o1 = fmaxf(a0.y + rA.y + bA.y, 0.f);
        float o2 = fmaxf(a0.z + rA.z + bA.z, 0.f);
        float o3 = fmaxf(a0.w + rA.w + bA.w, 0.f);
        float o4 = fmaxf(a1.x + rB.x + bB.x, 0.f);
        float o5 = fmaxf(a1.y + rB.y + bB.y, 0.f);
        float o6 = fmaxf(a1.z + rB.z + bB.z, 0.f);
        float o7 = fmaxf(a1.w + rB.w + bB.w, 0.f);
        uint4 o;
        o.x = bfpk(o0, o1); o.y = bfpk(o2, o3);
        o.z = bfpk(o4, o5); o.w = bfpk(o6, o7);
        xb[(size_t)n * 16 + ql] = o;
    }
}

// ---- 7: xw via MFMA: block = 64 nodes x 64 cols; wave = 16 cols, 4 node-subtiles ----
__global__ __launch_bounds__(256) void xw_mfma(const unsigned* __restrict__ xb,
                                               const unsigned* __restrict__ wtb,
                                               unsigned short* __restrict__ xwb) {
    int tid = threadIdx.x, wid = tid >> 6, l = tid & 63;
    int bn = blockIdx.x >> 2;            // node tile of 64
    int bc = blockIdx.x & 3;             // col quarter
    int col = bc * 64 + wid * 16 + (l & 15);
    int kq = l >> 4;                     // k-chunk within each K-step
    short8_t bfr[4];
    const unsigned* wcol = wtb + col * 64;
#pragma unroll
    for (int ks = 0; ks < 4; ++ks)
        bfr[ks] = *reinterpret_cast<const short8_t*>(wcol + ks * 16 + kq * 4);
    int n0 = bn * 64;
#pragma unroll
    for (int sub = 0; sub < 4; ++sub) {
        int row = n0 + sub * 16 + (l & 15);
        int rc = row < NN ? row : NN - 1;
        const unsigned* xr = xb + (size_t)rc * 64;
        f32x4_t acc = {0.f, 0.f, 0.f, 0.f};
#pragma unroll
        for (int ks = 0; ks < 4; ++ks) {
            short8_t a = *reinterpret_cast<const short8_t*>(xr + ks * 16 + kq * 4);
            acc = __builtin_amdgcn_mfma_f32_16x16x32_bf16(a, bfr[ks], acc, 0, 0, 0);
        }
        int orow0 = n0 + sub * 16 + kq * 4;
#pragma unroll
        for (int j = 0; j < 4; ++j) {
            int orow = orow0 + j;
            if (orow < NN) xwb[(size_t)orow * 256 + col] = bf16r(acc[j]);
        }
    }
}

// ---- 8: layer 2 (bf16 xw): wave/node; 8 lanes/edge; key prefetch pipeline ----
__global__ __launch_bounds__(256) void l2_gather(const unsigned* __restrict__ node_off,
                                                 const unsigned* __restrict__ srcr,
                                                 const float* __restrict__ inv,
                                                 const uint2* __restrict__ xwb,
                                                 const unsigned* __restrict__ xb,
                                                 const float* __restrict__ root2,
                                                 const float* __restrict__ bias2,
                                                 float* __restrict__ out) {
    int wid = threadIdx.x >> 6, lane = threadIdx.x & 63;
    int n = blockIdx.x * 4 + wid;
    if (n >= NN) return;
    int g = lane >> 3, gl = lane & 7;
    int beg = node_off[n], end = node_off[n + 1];
    int cnt = end - beg;
    int nfull = cnt >> 4;                    // 16 edges per full iteration
    float myinv = inv[n * RR + (lane & 7)];
    float4 acc = {0.f, 0.f, 0.f, 0.f};
    int e = beg + g;
    unsigned kp0 = srcr[e], kp1 = srcr[e + 8];
#define GATH2(K, C) {                                              \
        unsigned ss = (K) & 0xFFFFu, rr = (K) >> 16;               \
        uint2 v = xwb[((size_t)ss * RR + rr) * 8 + gl];            \
        acc.x = fmaf(bflo(v.x), (C), acc.x);                       \
        acc.y = fmaf(bfhi(v.x), (C), acc.y);                       \
        acc.z = fmaf(bflo(v.y), (C), acc.z);                       \
        acc.w = fmaf(bfhi(v.y), (C), acc.w); }
#pragma unroll 1
    for (int it = 0; it < nfull; ++it) {
        unsigned k0 = kp0, k1 = kp1;
        e += 16;
        kp0 = srcr[e]; kp1 = srcr[e + 8];
        float c0 = __shfl(myinv, (int)(k0 >> 16));
        float c1 = __shfl(myinv, (int)(k1 >> 16));
        GATH2(k0, c0);
        GATH2(k1, c1);
    }
    {   // tail: up to 15 edges; keys already prefetched
        float c0 = __shfl(myinv, (int)(kp0 >> 16));
        float c1 = __shfl(myinv, (int)(kp1 >> 16));
        if (e < end)     GATH2(kp0, c0);
        if (e + 8 < end) GATH2(kp1, c1);
    }
#undef GATH2
    // root2 part: group g covers h in [g*16, g*16+16), gl picks float4 of l
    {
        const uint4* xr = (const uint4*)(xb + (size_t)n * 64);
        uint4 u0 = xr[g * 2], u1 = xr[g * 2 + 1];
        float xv[16] = {bflo(u0.x), bfhi(u0.x), bflo(u0.y), bfhi(u0.y),
                        bflo(u0.z), bfhi(u0.z), bflo(u0.w), bfhi(u0.w),
                        bflo(u1.x), bfhi(u1.x), bflo(u1.y), bfhi(u1.y),
                        bflo(u1.z), bfhi(u1.z), bflo(u1.w), bfhi(u1.w)};
        const float4* rp = (const float4*)root2 + g * 16 * 8 + gl;
#pragma unroll
        for (int i = 0; i < 16; ++i) {
            float4 w = rp[i * 8];
            FMA4(acc, w, xv[i]);
        }
    }
#define RED3(c) { c += __shfl_xor(c, 8); c += __shfl_xor(c, 16); c += __shfl_xor(c, 32); }
    RED3(acc.x); RED3(acc.y); RED3(acc.z); RED3(acc.w);
#undef RED3
    if (lane < 8) {
        float4 b = ((const float4*)bias2)[gl];
        float4 z;
        z.x = 1.f / (1.f + expf(-(acc.x + b.x)));
        z.y = 1.f / (1.f + expf(-(acc.y + b.y)));
        z.z = 1.f / (1.f + expf(-(acc.z + b.z)));
        z.w = 1.f / (1.f + expf(-(acc.w + b.w)));
        ((float4*)(out + (size_t)n * LL))[gl] = z;
    }
}

extern "C" void kernel_launch(void* const* d_in, const int* in_sizes, int n_in,
                              void* d_out, int out_size, void* d_ws, size_t ws_size,
                              hipStream_t stream) {
    const float* w1    = (const float*)d_in[0];
    const float* root1 = (const float*)d_in[1];
    const float* bias1 = (const float*)d_in[2];
    const float* w2    = (const float*)d_in[3];
    const float* root2 = (const float*)d_in[4];
    const float* bias2 = (const float*)d_in[5];
    const int*   ei    = (const int*)d_in[6];
    const int*   et    = (const int*)d_in[7];
    float* out = (float*)d_out;

    // workspace layout (4-byte words; xb/wtb/w1b/xwb 16B-aligned)
    float*    inv      = (float*)d_ws;                     // @0        400000
    unsigned* node_off = (unsigned*)(inv + 400000);        // @400000   50004
    unsigned* boff     = node_off + 50004;                 // @450004   400
    unsigned* bcur     = boff + 400;                       // @450404   400
    unsigned* bcnt     = bcur + 400;                       // @450804   400
    unsigned* ph       = bcnt + 400;                       // @451204   305768
    unsigned* srcr     = ph + 305768;                      // @756972   1600020
    unsigned* xb       = srcr + 1600020;                   // @2356992  3200000 (bf16 x)
    unsigned* wtb      = xb + 3200000;                     // @5556992  16384   (bf16 W_T)
    unsigned* w1b      = wtb + 16384;                      // @5573376  25600000 (bf16 w1)
    unsigned* xwb      = w1b + 25600000;                   // @31173376 6400000  (bf16 xw)
    unsigned* tmp      = xwb;                              // alias: tmp dead before xwb written
    // end @37573376 words = 150.3 MB

    hist_kernel<<<PB, 256, 0, stream>>>(ei, ph);
    bred_kernel<<<NB, 256, 0, stream>>>(ph, bcnt);
    bscan_kernel<<<1, 512, 0, stream>>>(bcnt, boff, bcur, node_off, srcr);
    part_conv<<<PB + 25001, 256, 0, stream>>>(ei, et, bcur, tmp,
                                              (const float4*)w1, w2, (uint4*)w1b, wtb);
    finalize_kernel<<<NB, 256, 0, stream>>>(boff, tmp, node_off, inv, srcr);
    l1_gather<<<(NN + 3) / 4, 256, 0, stream>>>(node_off, srcr, inv, (const uint4*)w1b,
                                                root1, bias1, (uint4*)xb);
    xw_mfma<<<((NN + 63) / 64) * 4, 256, 0, stream>>>(xb, wtb, (unsigned short*)xwb);
    l2_gather<<<(NN + 3) / 4, 256, 0, stream>>>(node_off, srcr, inv, (const uint2*)xwb,
                                                xb, root2, bias2, out);
}